// Round 9
// baseline (193.801 us; speedup 1.0000x reference)
//
#include <hip/hip_runtime.h>

#define SEQ 2048
#define DMODEL 2048

typedef __attribute__((ext_vector_type(8))) _Float16 half8;
typedef __attribute__((ext_vector_type(4))) float f32x4;
typedef __attribute__((ext_vector_type(16))) float f32x16;

typedef const __attribute__((address_space(1))) void* gptr_t;
typedef __attribute__((address_space(3))) void* lptr_t;

static __device__ __forceinline__ void gload16(const void* g, void* l) {
  __builtin_amdgcn_global_load_lds((gptr_t)g, (lptr_t)l, 16, 0, 0);
}

static __device__ __forceinline__ unsigned short f2h(float f) {
  _Float16 h = (_Float16)f;
  union { _Float16 h; unsigned short u; } v; v.h = h;
  return v.u;
}

static __device__ __forceinline__ unsigned int pkh2(float a, float b) {
  union { __fp16 __attribute__((ext_vector_type(2))) h; unsigned int u; } v;
  v.h = __builtin_amdgcn_cvt_pkrtz(a, b);
  return v.u;
}

// ---------------- elementwise fp32 -> fp16 ----------------
__global__ void k_cvt(const float* __restrict__ in, unsigned short* __restrict__ out, int n) {
  int i = (blockIdx.x * 256 + threadIdx.x) * 4;
  if (i >= n) return;
  float4 v = *(const float4*)(in + i);
  ushort4 o;
  o.x = f2h(v.x); o.y = f2h(v.y); o.z = f2h(v.z); o.w = f2h(v.w);
  *(ushort4*)(out + i) = o;
}

// ---------------- tiled transpose + convert: in fp32 [K][N] -> out fp16 [N][K] ----------------
__global__ void k_tcvt(const float* __restrict__ in, unsigned short* __restrict__ out,
                       int K, int N, int ldin) {
  __shared__ float tile[32][33];
  int n0 = blockIdx.x * 32, k0 = blockIdx.y * 32;
  int tx = threadIdx.x, ty = threadIdx.y;  // 32 x 8
  #pragma unroll
  for (int j = ty; j < 32; j += 8)
    tile[j][tx] = in[(long)(k0 + j) * ldin + n0 + tx];
  __syncthreads();
  #pragma unroll
  for (int j = ty; j < 32; j += 8)
    out[(long)(n0 + j) * K + k0 + tx] = f2h(tile[tx][j]);
}

// ---------------- V transpose fp16 [S][512] -> Vt [8][64][S] with key permutation ----------------
// pos(s) within each 16: swap bits 2 and 3 (involution) to match the PV A-fragment natural order.
__global__ void k_tvp(const unsigned short* __restrict__ in, unsigned short* __restrict__ out) {
  __shared__ unsigned short tile[32][33];
  int c0 = blockIdx.x * 32, s0 = blockIdx.y * 32;
  int tx = threadIdx.x, ty = threadIdx.y;  // 32 x 8
  #pragma unroll
  for (int j = ty; j < 32; j += 8)
    tile[j][tx] = in[(long)(s0 + j) * 512 + c0 + tx];
  __syncthreads();
  #pragma unroll
  for (int j = ty; j < 32; j += 8) {
    int c = c0 + j;
    int s = s0 + tx;
    int sp = (s & ~12) | ((s & 8) >> 1) | ((s & 4) << 1);
    out[((long)(c >> 6) * 64 + (c & 63)) * SEQ + sp] = tile[tx][j];
  }
}

// ---------------- GEMM core: 128x128 tile, BK=32, 8 waves (4m x 2n), depth-2 ring ----------------
static __device__ __forceinline__ void gemm_core(const unsigned short* __restrict__ A,
                                                 const unsigned short* __restrict__ B,
                                                 int K, unsigned short* As, unsigned short* Bs,
                                                 long m0, long n0, int t, int wm, int wn,
                                                 int lr, int lh, f32x4 acc[2][4]) {
  const unsigned short* Ag = A + (m0 + (t >> 2)) * K + (t & 3) * 8;
  const unsigned short* Bg = B + (n0 + (t >> 2)) * K + (t & 3) * 8;
  #pragma unroll
  for (int i = 0; i < 2; i++)
    #pragma unroll
    for (int j = 0; j < 4; j++)
      acc[i][j] = (f32x4){0.f, 0.f, 0.f, 0.f};

#define STAGE(buf, k0) do { \
    gload16(Ag + (k0), As + (buf) * 4096 + t * 8); \
    gload16(Bg + (k0), Bs + (buf) * 4096 + t * 8); \
  } while (0)

  int T = K >> 5;
  STAGE(0, 0);
  STAGE(1, 32);
  asm volatile("s_waitcnt vmcnt(2)" ::: "memory");
  __builtin_amdgcn_s_barrier();

  int bi = 0;
  for (int ti = 0; ti < T; ti++) {
    if (ti + 2 < T) STAGE((bi + 2) % 3, (ti + 2) * 32);
    const unsigned short* Ab = As + bi * 4096;
    const unsigned short* Bb = Bs + bi * 4096;
    half8 a[2], b[4];
    #pragma unroll
    for (int mf = 0; mf < 2; mf++)
      a[mf] = *(const half8*)&Ab[(wm * 32 + mf * 16 + lr) * 32 + lh * 8];
    #pragma unroll
    for (int nf = 0; nf < 4; nf++)
      b[nf] = *(const half8*)&Bb[(wn * 64 + nf * 16 + lr) * 32 + lh * 8];
    #pragma unroll
    for (int mf = 0; mf < 2; mf++)
      #pragma unroll
      for (int nf = 0; nf < 4; nf++)
        acc[mf][nf] = __builtin_amdgcn_mfma_f32_16x16x32_f16(a[mf], b[nf], acc[mf][nf], 0, 0, 0);
    if (ti + 2 < T) asm volatile("s_waitcnt vmcnt(2)" ::: "memory");
    else            asm volatile("s_waitcnt vmcnt(0)" ::: "memory");
    __builtin_amdgcn_s_barrier();
    bi = bi == 2 ? 0 : bi + 1;
  }
#undef STAGE
}

// plain fp32-C GEMM (output projection)
__global__ __launch_bounds__(512) void k_gemm(const unsigned short* __restrict__ A,
                                              const unsigned short* __restrict__ B,
                                              float* __restrict__ C, int M, int N, int K) {
  __shared__ unsigned short As[3 * 4096];
  __shared__ unsigned short Bs[3 * 4096];
  int t = threadIdx.x;
  int l = t & 63, w = t >> 6;
  int wm = w >> 1, wn = w & 1;
  int lr = l & 15, lh = l >> 4;
  long m0 = (long)blockIdx.y * 128, n0 = (long)blockIdx.x * 128;
  f32x4 acc[2][4];
  gemm_core(A, B, K, As, Bs, m0, n0, t, wm, wn, lr, lh, acc);
  #pragma unroll
  for (int mf = 0; mf < 2; mf++)
    #pragma unroll
    for (int nf = 0; nf < 4; nf++)
      #pragma unroll
      for (int i = 0; i < 4; i++)
        C[(m0 + wm * 32 + mf * 16 + lh * 4 + i) * N + n0 + wn * 64 + nf * 16 + lr] = acc[mf][nf][i];
}

// QKV GEMM with fused RoPE + fp16 conversion + layout epilogue.
// cols 0..2047 -> Qr [S][2048] (rope, scaled); 2048..2559 -> Kr [8][S][64] (rope);
// 2560..3071 -> Vr [S][512] (plain fp16).
__global__ __launch_bounds__(512) void k_gemm_qkv(const unsigned short* __restrict__ A,
                                                  const unsigned short* __restrict__ B,
                                                  unsigned short* __restrict__ Qr,
                                                  unsigned short* __restrict__ Kr,
                                                  unsigned short* __restrict__ Vr,
                                                  const float* __restrict__ fc,
                                                  const float* __restrict__ fs, int K) {
  __shared__ unsigned short As[3 * 4096];
  __shared__ unsigned short Bs[3 * 4096];
  int t = threadIdx.x;
  int l = t & 63, w = t >> 6;
  int wm = w >> 1, wn = w & 1;
  int lr = l & 15, lh = l >> 4;
  long m0 = (long)blockIdx.y * 128, n0 = (long)blockIdx.x * 128;
  f32x4 acc[2][4];
  gemm_core(A, B, K, As, Bs, m0, n0, t, wm, wn, lr, lh, acc);

  const float SC = 0.125f * 1.44269504f;
  int n0i = (int)n0;
  if (n0i < 2560) {
    bool isQ = n0i < 2048;
    float scl = isQ ? SC : 1.0f;
    #pragma unroll
    for (int mf = 0; mf < 2; mf++)
      #pragma unroll
      for (int i = 0; i < 4; i++) {
        int row = (int)m0 + wm * 32 + mf * 16 + lh * 4 + i;
        const float* fcr = fc + row * 32;
        const float* fsr = fs + row * 32;
        #pragma unroll
        for (int nf = 0; nf < 4; nf++) {
          float v = acc[mf][nf][i];
          float pv = __shfl_xor(v, 1);
          int col = n0i + wn * 64 + nf * 16 + lr;
          int j = (col & 63) >> 1;
          float c_ = fcr[j] * scl, s_ = fsr[j] * scl;
          float o = (lr & 1) ? (pv * s_ + v * c_) : (v * c_ - pv * s_);
          if (isQ) Qr[(long)row * 2048 + col] = f2h(o);
          else {
            int cc = col - 2048;
            Kr[((long)(cc >> 6) * SEQ + row) * 64 + (cc & 63)] = f2h(o);
          }
        }
      }
  } else {
    #pragma unroll
    for (int mf = 0; mf < 2; mf++)
      #pragma unroll
      for (int i = 0; i < 4; i++) {
        int row = (int)m0 + wm * 32 + mf * 16 + lh * 4 + i;
        #pragma unroll
        for (int nf = 0; nf < 4; nf++) {
          int col = n0i + wn * 64 + nf * 16 + lr;
          Vr[(long)row * 512 + (col - 2560)] = f2h(acc[mf][nf][i]);
        }
      }
  }
}

// ---------------- causal GQA flash attention: LDS-staged K/V, ring-3 pipeline ----------------
// Block = (head, 128 q-rows); 4 waves x 32 q-rows. KV-tiles staged coalesced into LDS
// (K 4KB + V 4KB per tile, 2 global_load_lds per block-tile), ring of 3, counted vmcnt.
// Fragments via ds_read_b128 with XOR swizzle (K: ^((row&7)<<4) bytes; V: ^((row&3)<<4)).
// No-max softmax: P = exp2(S - 8). V global layout is key-permuted (k_tvp) so P regs feed PV.
__global__ __launch_bounds__(256) void k_attn(const unsigned short* __restrict__ Qr,
                                              const unsigned short* __restrict__ Kr,
                                              const unsigned short* __restrict__ Vg,
                                              unsigned short* __restrict__ AO) {
  __shared__ unsigned short KT[3][2048];  // [32 keys][64 d] swizzled
  __shared__ unsigned short VT[3][2048];  // [64 d][32 keys] swizzled
  __shared__ float gbuf[4][32];

  int tt = threadIdx.x;
  int wid = tt >> 6, l = tt & 63;
  int q = l & 31, hs = l >> 5;
  int h = blockIdx.x, hkv = h >> 2;
  int by = (int)gridDim.y - 1 - blockIdx.y;  // longest blocks dispatch first
  int tmax = 4 * by + 3;                     // last kv-tile staged by this block
  int dt = 4 * by + wid;                     // this wave's diagonal tile
  int q0 = by * 128 + wid * 32;

  const unsigned short* Kh = Kr + (long)hkv * SEQ * 64;
  const unsigned short* Vh = Vg + (long)hkv * 64 * SEQ;

  // staging source addresses (pre-swizzled global so LDS dest stays linear)
  int skr = tt >> 3, skc = tt & 7;  // K: row (key), 16B-chunk
  int svr = tt >> 2, svc = tt & 3;  // V: row (d), 16B-chunk
  const unsigned short* Ksrc = Kh + (long)skr * 64 + ((skc * 8) ^ ((skr & 7) << 3));
  const unsigned short* Vsrc = Vh + (long)svr * SEQ + ((svc * 8) ^ ((svr & 3) << 3));

  auto ASTAGE = [&](int buf, int ti) {
    int t0 = ti * 32;
    gload16(Ksrc + (long)t0 * 64, &KT[buf][tt * 8]);
    gload16(Vsrc + t0, &VT[buf][tt * 8]);
  };

  // Q fragments (B-operand of swapped QK^T), hoisted
  half8 Qf[4];
  #pragma unroll
  for (int d = 0; d < 4; d++)
    Qf[d] = *(const half8*)&Qr[(long)(q0 + q) * 2048 + h * 64 + d * 16 + 8 * hs];

  f32x16 O0, O1;
  #pragma unroll
  for (int r = 0; r < 16; r++) { O0[r] = 0.f; O1[r] = 0.f; }
  float lsum = 0.f;

  ASTAGE(0, 0);
  ASTAGE(1, 1);
  asm volatile("s_waitcnt vmcnt(2)" ::: "memory");
  __builtin_amdgcn_s_barrier();

  for (int ti = 0; ti <= tmax; ti++) {
    int bi = ti % 3;
    if (ti + 2 <= tmax) ASTAGE((ti + 2) % 3, ti + 2);

    if (ti <= dt) {
      const unsigned short* Ks = KT[bi];
      const unsigned short* Vs = VT[bi];
      half8 Kf[4], Vf[2][2];
      #pragma unroll
      for (int d = 0; d < 4; d++) {
        int e0 = d * 16 + 8 * hs;
        Kf[d] = *(const half8*)&Ks[q * 64 + (e0 ^ ((q & 7) << 3))];
      }
      #pragma unroll
      for (int ks = 0; ks < 2; ks++)
        #pragma unroll
        for (int nf = 0; nf < 2; nf++) {
          int d = q + 32 * nf;
          int e0 = ks * 16 + 8 * hs;
          Vf[ks][nf] = *(const half8*)&Vs[d * 32 + (e0 ^ ((d & 3) << 3))];
        }

      f32x16 S;
      #pragma unroll
      for (int r = 0; r < 16; r++) S[r] = 0.f;
      #pragma unroll
      for (int d = 0; d < 4; d++)
        S = __builtin_amdgcn_mfma_f32_32x32x16_f16(Kf[d], Qf[d], S, 0, 0, 0);

      bool dg = (ti == dt);
      float p[16];
      #pragma unroll
      for (int r = 0; r < 16; r++) {
        float v = S[r];
        if (dg) {
          int key = (r & 3) + 8 * (r >> 2) + 4 * hs;
          if (key > q) v = -1e30f;
        }
        p[r] = __builtin_exp2f(v - 8.0f);
        lsum += p[r];
      }

      union { unsigned int u[4]; half8 hh; } f0, f1;
      #pragma unroll
      for (int c = 0; c < 4; c++) {
        f0.u[c] = pkh2(p[2 * c], p[2 * c + 1]);
        f1.u[c] = pkh2(p[8 + 2 * c], p[9 + 2 * c]);
      }

      O0 = __builtin_amdgcn_mfma_f32_32x32x16_f16(f0.hh, Vf[0][0], O0, 0, 0, 0);
      O0 = __builtin_amdgcn_mfma_f32_32x32x16_f16(f1.hh, Vf[1][0], O0, 0, 0, 0);
      O1 = __builtin_amdgcn_mfma_f32_32x32x16_f16(f0.hh, Vf[0][1], O1, 0, 0, 0);
      O1 = __builtin_amdgcn_mfma_f32_32x32x16_f16(f1.hh, Vf[1][1], O1, 0, 0, 0);
    }

    if (ti + 2 <= tmax) asm volatile("s_waitcnt vmcnt(2)" ::: "memory");
    else                asm volatile("s_waitcnt vmcnt(0)" ::: "memory");
    __builtin_amdgcn_s_barrier();
  }

  // per-wave normalization (no cross-wave merge)
  lsum += __shfl_xor(lsum, 32);
  if (l < 32) gbuf[wid][l] = 1.f / lsum;
  asm volatile("" ::: "memory");
  #pragma unroll
  for (int r = 0; r < 16; r++) {
    int row = (r & 3) + 8 * (r >> 2) + 4 * hs;
    float ri = gbuf[wid][row];
    AO[(long)(q0 + row) * 2048 + h * 64 + q] = f2h(O0[r] * ri);
    AO[(long)(q0 + row) * 2048 + h * 64 + q + 32] = f2h(O1[r] * ri);
  }
}

extern "C" void kernel_launch(void* const* d_in, const int* in_sizes, int n_in,
                              void* d_out, int out_size, void* d_ws, size_t ws_size,
                              hipStream_t stream) {
  const float* x  = (const float*)d_in[0];
  const float* fc = (const float*)d_in[1];
  const float* fs = (const float*)d_in[2];
  const float* Wq = (const float*)d_in[4];
  const float* Wk = (const float*)d_in[5];
  const float* Wv = (const float*)d_in[6];
  const float* Wo = (const float*)d_in[7];
  float* out = (float*)d_out;

  char* ws = (char*)d_ws;
  unsigned short* xb  = (unsigned short*)(ws);                  // 8 MB (reused as AO later)
  unsigned short* WT  = (unsigned short*)(ws + (8l  << 20));    // 12 MB  [3072][2048] fp16
  unsigned short* WoT = (unsigned short*)(ws + (20l << 20));    // 8 MB   [2048][2048] fp16
  unsigned short* Qr  = (unsigned short*)(ws + (28l << 20));    // 8 MB   [S][2048] fp16
  unsigned short* Kr  = (unsigned short*)(ws + (36l << 20));    // 2 MB   [8][S][64] fp16
  unsigned short* Vr  = (unsigned short*)(ws + (38l << 20));    // 2 MB   [S][512] fp16
  unsigned short* Vt  = (unsigned short*)(ws + (40l << 20));    // 2 MB   [8][64][S] fp16 (key-permuted)
  unsigned short* AO  = xb;                                     // overlay: xb dead after QKV GEMM

  dim3 tb(32, 8);
  k_cvt<<<4096, 256, 0, stream>>>(x, xb, 2048 * 2048);
  k_tcvt<<<dim3(64, 64), tb, 0, stream>>>(Wq, WT, 2048, 2048, 2048);
  k_tcvt<<<dim3(16, 64), tb, 0, stream>>>(Wk, WT + 2048l * 2048, 2048, 512, 512);
  k_tcvt<<<dim3(16, 64), tb, 0, stream>>>(Wv, WT + 2560l * 2048, 2048, 512, 512);
  k_tcvt<<<dim3(64, 64), tb, 0, stream>>>(Wo, WoT, 2048, 2048, 2048);

  k_gemm_qkv<<<dim3(24, 16), 512, 0, stream>>>(xb, WT, Qr, Kr, Vr, fc, fs, 2048);

  k_tvp<<<dim3(16, 64), tb, 0, stream>>>(Vr, Vt);

  k_attn<<<dim3(32, 16), 256, 0, stream>>>(Qr, Kr, Vt, AO);

  k_gemm<<<dim3(16, 16), 512, 0, stream>>>(AO, WoT, out, 2048, 2048, 2048);
}

// Round 10
// 174.410 us; speedup vs baseline: 1.1112x; 1.1112x over previous
//
#include <hip/hip_runtime.h>

#define SEQ 2048
#define DMODEL 2048

typedef __attribute__((ext_vector_type(8))) _Float16 half8;
typedef __attribute__((ext_vector_type(4))) float f32x4;
typedef __attribute__((ext_vector_type(16))) float f32x16;

typedef const __attribute__((address_space(1))) void* gptr_t;
typedef __attribute__((address_space(3))) void* lptr_t;

static __device__ __forceinline__ void gload16(const void* g, void* l) {
  __builtin_amdgcn_global_load_lds((gptr_t)g, (lptr_t)l, 16, 0, 0);
}

static __device__ __forceinline__ unsigned short f2h(float f) {
  _Float16 h = (_Float16)f;
  union { _Float16 h; unsigned short u; } v; v.h = h;
  return v.u;
}

static __device__ __forceinline__ unsigned int pkh2(float a, float b) {
  union { __fp16 __attribute__((ext_vector_type(2))) h; unsigned int u; } v;
  v.h = __builtin_amdgcn_cvt_pkrtz(a, b);
  return v.u;
}

// ---------------- elementwise fp32 -> fp16 ----------------
__global__ void k_cvt(const float* __restrict__ in, unsigned short* __restrict__ out, int n) {
  int i = (blockIdx.x * 256 + threadIdx.x) * 4;
  if (i >= n) return;
  float4 v = *(const float4*)(in + i);
  ushort4 o;
  o.x = f2h(v.x); o.y = f2h(v.y); o.z = f2h(v.z); o.w = f2h(v.w);
  *(ushort4*)(out + i) = o;
}

// ---------------- tiled transpose + convert: in fp32 [K][N] -> out fp16 [N][K] ----------------
__global__ void k_tcvt(const float* __restrict__ in, unsigned short* __restrict__ out,
                       int K, int N, int ldin) {
  __shared__ float tile[32][33];
  int n0 = blockIdx.x * 32, k0 = blockIdx.y * 32;
  int tx = threadIdx.x, ty = threadIdx.y;  // 32 x 8
  #pragma unroll
  for (int j = ty; j < 32; j += 8)
    tile[j][tx] = in[(long)(k0 + j) * ldin + n0 + tx];
  __syncthreads();
  #pragma unroll
  for (int j = ty; j < 32; j += 8)
    out[(long)(n0 + j) * K + k0 + tx] = f2h(tile[tx][j]);
}

// ---------------- V transpose fp16 [S][512] -> Vt [8][64][S] with key permutation ----------------
__global__ void k_tvp(const unsigned short* __restrict__ in, unsigned short* __restrict__ out) {
  __shared__ unsigned short tile[32][33];
  int c0 = blockIdx.x * 32, s0 = blockIdx.y * 32;
  int tx = threadIdx.x, ty = threadIdx.y;  // 32 x 8
  #pragma unroll
  for (int j = ty; j < 32; j += 8)
    tile[j][tx] = in[(long)(s0 + j) * 512 + c0 + tx];
  __syncthreads();
  #pragma unroll
  for (int j = ty; j < 32; j += 8) {
    int c = c0 + j;
    int s = s0 + tx;
    int sp = (s & ~12) | ((s & 8) >> 1) | ((s & 4) << 1);
    out[((long)(c >> 6) * 64 + (c & 63)) * SEQ + sp] = tile[tx][j];
  }
}

// ---------------- GEMM core: 128x128 tile, BK=32, 8 waves (4m x 2n), depth-2 ring ----------------
static __device__ __forceinline__ void gemm_core(const unsigned short* __restrict__ A,
                                                 const unsigned short* __restrict__ B,
                                                 int K, unsigned short* As, unsigned short* Bs,
                                                 long m0, long n0, int t, int wm, int wn,
                                                 int lr, int lh, f32x4 acc[2][4]) {
  const unsigned short* Ag = A + (m0 + (t >> 2)) * K + (t & 3) * 8;
  const unsigned short* Bg = B + (n0 + (t >> 2)) * K + (t & 3) * 8;
  #pragma unroll
  for (int i = 0; i < 2; i++)
    #pragma unroll
    for (int j = 0; j < 4; j++)
      acc[i][j] = (f32x4){0.f, 0.f, 0.f, 0.f};

#define STAGE(buf, k0) do { \
    gload16(Ag + (k0), As + (buf) * 4096 + t * 8); \
    gload16(Bg + (k0), Bs + (buf) * 4096 + t * 8); \
  } while (0)

  int T = K >> 5;
  STAGE(0, 0);
  STAGE(1, 32);
  asm volatile("s_waitcnt vmcnt(2)" ::: "memory");
  __builtin_amdgcn_s_barrier();

  int bi = 0;
  for (int ti = 0; ti < T; ti++) {
    if (ti + 2 < T) STAGE((bi + 2) % 3, (ti + 2) * 32);
    const unsigned short* Ab = As + bi * 4096;
    const unsigned short* Bb = Bs + bi * 4096;
    half8 a[2], b[4];
    #pragma unroll
    for (int mf = 0; mf < 2; mf++)
      a[mf] = *(const half8*)&Ab[(wm * 32 + mf * 16 + lr) * 32 + lh * 8];
    #pragma unroll
    for (int nf = 0; nf < 4; nf++)
      b[nf] = *(const half8*)&Bb[(wn * 64 + nf * 16 + lr) * 32 + lh * 8];
    #pragma unroll
    for (int mf = 0; mf < 2; mf++)
      #pragma unroll
      for (int nf = 0; nf < 4; nf++)
        acc[mf][nf] = __builtin_amdgcn_mfma_f32_16x16x32_f16(a[mf], b[nf], acc[mf][nf], 0, 0, 0);
    if (ti + 2 < T) asm volatile("s_waitcnt vmcnt(2)" ::: "memory");
    else            asm volatile("s_waitcnt vmcnt(0)" ::: "memory");
    __builtin_amdgcn_s_barrier();
    bi = bi == 2 ? 0 : bi + 1;
  }
#undef STAGE
}

// plain fp32-C GEMM (output projection)
__global__ __launch_bounds__(512) void k_gemm(const unsigned short* __restrict__ A,
                                              const unsigned short* __restrict__ B,
                                              float* __restrict__ C, int M, int N, int K) {
  __shared__ unsigned short As[3 * 4096];
  __shared__ unsigned short Bs[3 * 4096];
  int t = threadIdx.x;
  int l = t & 63, w = t >> 6;
  int wm = w >> 1, wn = w & 1;
  int lr = l & 15, lh = l >> 4;
  long m0 = (long)blockIdx.y * 128, n0 = (long)blockIdx.x * 128;
  f32x4 acc[2][4];
  gemm_core(A, B, K, As, Bs, m0, n0, t, wm, wn, lr, lh, acc);
  #pragma unroll
  for (int mf = 0; mf < 2; mf++)
    #pragma unroll
    for (int nf = 0; nf < 4; nf++)
      #pragma unroll
      for (int i = 0; i < 4; i++)
        C[(m0 + wm * 32 + mf * 16 + lh * 4 + i) * N + n0 + wn * 64 + nf * 16 + lr] = acc[mf][nf][i];
}

// QKV GEMM with fused RoPE + fp16 conversion + layout epilogue.
__global__ __launch_bounds__(512) void k_gemm_qkv(const unsigned short* __restrict__ A,
                                                  const unsigned short* __restrict__ B,
                                                  unsigned short* __restrict__ Qr,
                                                  unsigned short* __restrict__ Kr,
                                                  unsigned short* __restrict__ Vr,
                                                  const float* __restrict__ fc,
                                                  const float* __restrict__ fs, int K) {
  __shared__ unsigned short As[3 * 4096];
  __shared__ unsigned short Bs[3 * 4096];
  int t = threadIdx.x;
  int l = t & 63, w = t >> 6;
  int wm = w >> 1, wn = w & 1;
  int lr = l & 15, lh = l >> 4;
  long m0 = (long)blockIdx.y * 128, n0 = (long)blockIdx.x * 128;
  f32x4 acc[2][4];
  gemm_core(A, B, K, As, Bs, m0, n0, t, wm, wn, lr, lh, acc);

  const float SC = 0.125f * 1.44269504f;
  int n0i = (int)n0;
  if (n0i < 2560) {
    bool isQ = n0i < 2048;
    float scl = isQ ? SC : 1.0f;
    #pragma unroll
    for (int mf = 0; mf < 2; mf++)
      #pragma unroll
      for (int i = 0; i < 4; i++) {
        int row = (int)m0 + wm * 32 + mf * 16 + lh * 4 + i;
        const float* fcr = fc + row * 32;
        const float* fsr = fs + row * 32;
        #pragma unroll
        for (int nf = 0; nf < 4; nf++) {
          float v = acc[mf][nf][i];
          float pv = __shfl_xor(v, 1);
          int col = n0i + wn * 64 + nf * 16 + lr;
          int j = (col & 63) >> 1;
          float c_ = fcr[j] * scl, s_ = fsr[j] * scl;
          float o = (lr & 1) ? (pv * s_ + v * c_) : (v * c_ - pv * s_);
          if (isQ) Qr[(long)row * 2048 + col] = f2h(o);
          else {
            int cc = col - 2048;
            Kr[((long)(cc >> 6) * SEQ + row) * 64 + (cc & 63)] = f2h(o);
          }
        }
      }
  } else {
    #pragma unroll
    for (int mf = 0; mf < 2; mf++)
      #pragma unroll
      for (int i = 0; i < 4; i++) {
        int row = (int)m0 + wm * 32 + mf * 16 + lh * 4 + i;
        #pragma unroll
        for (int nf = 0; nf < 4; nf++) {
          int col = n0i + wn * 64 + nf * 16 + lr;
          Vr[(long)row * 512 + (col - 2560)] = f2h(acc[mf][nf][i]);
        }
      }
  }
}

// ---------------- causal GQA flash attention: KVBLK=128 super-tiles, double-buffered LDS ----------------
// Block = (head, 128 q-rows); 4 waves x 32 q-rows. Per phase: stage 4 KV sub-tiles (16KB K + 16KB V),
// one vmcnt(0)+barrier per SUPER (not per sub-tile) -> 16 barriers max instead of 64.
// Sub-tile compute identical to R9: swapped QK^T 32x32, no-max softmax P=exp2(S-8), key-permuted V.
__global__ __launch_bounds__(256) void k_attn(const unsigned short* __restrict__ Qr,
                                              const unsigned short* __restrict__ Kr,
                                              const unsigned short* __restrict__ Vg,
                                              unsigned short* __restrict__ AO) {
  __shared__ unsigned short KT[2][8192];  // 2 x [4 subtiles][32 keys][64 d] swizzled
  __shared__ unsigned short VT[2][8192];  // 2 x [4 subtiles][64 d][32 keys] swizzled
  __shared__ float gbuf[4][32];

  int tt = threadIdx.x;
  int wid = tt >> 6, l = tt & 63;
  int q = l & 31, hs = l >> 5;
  int h = blockIdx.x, hkv = h >> 2;
  int by = (int)gridDim.y - 1 - blockIdx.y;  // longest blocks dispatch first
  int dt = 4 * by + wid;                     // this wave's diagonal kv-tile
  int q0 = by * 128 + wid * 32;

  const unsigned short* Kh = Kr + (long)hkv * SEQ * 64;
  const unsigned short* Vh = Vg + (long)hkv * 64 * SEQ;

  // staging source addresses (pre-swizzled global so LDS dest stays linear)
  int skr = tt >> 3, skc = tt & 7;  // K: row (key), 16B-chunk
  int svr = tt >> 2, svc = tt & 3;  // V: row (d), 16B-chunk
  const unsigned short* Ksrc = Kh + (long)skr * 64 + ((skc * 8) ^ ((skr & 7) << 3));
  const unsigned short* Vsrc = Vh + (long)svr * SEQ + ((svc * 8) ^ ((svr & 3) << 3));

#define ASTAGE(si) do { \
    int buf_ = (si) & 1; \
    _Pragma("unroll") for (int sub_ = 0; sub_ < 4; sub_++) { \
      int t0_ = ((si) * 4 + sub_) * 32; \
      gload16(Ksrc + (long)t0_ * 64, &KT[buf_][sub_ * 2048 + tt * 8]); \
      gload16(Vsrc + t0_, &VT[buf_][sub_ * 2048 + tt * 8]); \
    } \
  } while (0)

  // Q fragments (B-operand of swapped QK^T), hoisted
  half8 Qf[4];
  #pragma unroll
  for (int d = 0; d < 4; d++)
    Qf[d] = *(const half8*)&Qr[(long)(q0 + q) * 2048 + h * 64 + d * 16 + 8 * hs];

  f32x16 O0, O1;
  #pragma unroll
  for (int r = 0; r < 16; r++) { O0[r] = 0.f; O1[r] = 0.f; }
  float lsum = 0.f;

  ASTAGE(0);
  asm volatile("s_waitcnt vmcnt(0)" ::: "memory");
  __builtin_amdgcn_s_barrier();

  for (int si = 0; si <= by; si++) {
    if (si + 1 <= by) ASTAGE(si + 1);  // issue next super early; drained at end of this one

    int buf = si & 1;
    #pragma unroll
    for (int sub = 0; sub < 4; sub++) {
      int ti = si * 4 + sub;
      if (ti <= dt) {
        const unsigned short* Ks = &KT[buf][sub * 2048];
        const unsigned short* Vs = &VT[buf][sub * 2048];
        half8 Kf[4], Vf[2][2];
        #pragma unroll
        for (int d = 0; d < 4; d++) {
          int e0 = d * 16 + 8 * hs;
          Kf[d] = *(const half8*)&Ks[q * 64 + (e0 ^ ((q & 7) << 3))];
        }
        #pragma unroll
        for (int ks = 0; ks < 2; ks++)
          #pragma unroll
          for (int nf = 0; nf < 2; nf++) {
            int d = q + 32 * nf;
            int e0 = ks * 16 + 8 * hs;
            Vf[ks][nf] = *(const half8*)&Vs[d * 32 + (e0 ^ ((d & 3) << 3))];
          }

        f32x16 S;
        #pragma unroll
        for (int r = 0; r < 16; r++) S[r] = 0.f;
        #pragma unroll
        for (int d = 0; d < 4; d++)
          S = __builtin_amdgcn_mfma_f32_32x32x16_f16(Kf[d], Qf[d], S, 0, 0, 0);

        bool dg = (ti == dt);
        float p[16];
        #pragma unroll
        for (int r = 0; r < 16; r++) {
          float v = S[r];
          if (dg) {
            int key = (r & 3) + 8 * (r >> 2) + 4 * hs;
            if (key > q) v = -1e30f;
          }
          p[r] = __builtin_exp2f(v - 8.0f);
          lsum += p[r];
        }

        union { unsigned int u[4]; half8 hh; } f0, f1;
        #pragma unroll
        for (int c = 0; c < 4; c++) {
          f0.u[c] = pkh2(p[2 * c], p[2 * c + 1]);
          f1.u[c] = pkh2(p[8 + 2 * c], p[9 + 2 * c]);
        }

        O0 = __builtin_amdgcn_mfma_f32_32x32x16_f16(f0.hh, Vf[0][0], O0, 0, 0, 0);
        O0 = __builtin_amdgcn_mfma_f32_32x32x16_f16(f1.hh, Vf[1][0], O0, 0, 0, 0);
        O1 = __builtin_amdgcn_mfma_f32_32x32x16_f16(f0.hh, Vf[0][1], O1, 0, 0, 0);
        O1 = __builtin_amdgcn_mfma_f32_32x32x16_f16(f1.hh, Vf[1][1], O1, 0, 0, 0);
      }
    }

    asm volatile("s_waitcnt vmcnt(0)" ::: "memory");  // next super's loads: issued ~4 subtiles ago
    __builtin_amdgcn_s_barrier();
  }
#undef ASTAGE

  // per-wave normalization (no cross-wave merge)
  lsum += __shfl_xor(lsum, 32);
  if (l < 32) gbuf[wid][l] = 1.f / lsum;
  asm volatile("" ::: "memory");
  #pragma unroll
  for (int r = 0; r < 16; r++) {
    int row = (r & 3) + 8 * (r >> 2) + 4 * hs;
    float ri = gbuf[wid][row];
    AO[(long)(q0 + row) * 2048 + h * 64 + q] = f2h(O0[r] * ri);
    AO[(long)(q0 + row) * 2048 + h * 64 + q + 32] = f2h(O1[r] * ri);
  }
}

extern "C" void kernel_launch(void* const* d_in, const int* in_sizes, int n_in,
                              void* d_out, int out_size, void* d_ws, size_t ws_size,
                              hipStream_t stream) {
  const float* x  = (const float*)d_in[0];
  const float* fc = (const float*)d_in[1];
  const float* fs = (const float*)d_in[2];
  const float* Wq = (const float*)d_in[4];
  const float* Wk = (const float*)d_in[5];
  const float* Wv = (const float*)d_in[6];
  const float* Wo = (const float*)d_in[7];
  float* out = (float*)d_out;

  char* ws = (char*)d_ws;
  unsigned short* xb  = (unsigned short*)(ws);                  // 8 MB (reused as AO later)
  unsigned short* WT  = (unsigned short*)(ws + (8l  << 20));    // 12 MB  [3072][2048] fp16
  unsigned short* WoT = (unsigned short*)(ws + (20l << 20));    // 8 MB   [2048][2048] fp16
  unsigned short* Qr  = (unsigned short*)(ws + (28l << 20));    // 8 MB   [S][2048] fp16
  unsigned short* Kr  = (unsigned short*)(ws + (36l << 20));    // 2 MB   [8][S][64] fp16
  unsigned short* Vr  = (unsigned short*)(ws + (38l << 20));    // 2 MB   [S][512] fp16
  unsigned short* Vt  = (unsigned short*)(ws + (40l << 20));    // 2 MB   [8][64][S] fp16 (key-permuted)
  unsigned short* AO  = xb;                                     // overlay: xb dead after QKV GEMM

  dim3 tb(32, 8);
  k_cvt<<<4096, 256, 0, stream>>>(x, xb, 2048 * 2048);
  k_tcvt<<<dim3(64, 64), tb, 0, stream>>>(Wq, WT, 2048, 2048, 2048);
  k_tcvt<<<dim3(16, 64), tb, 0, stream>>>(Wk, WT + 2048l * 2048, 2048, 512, 512);
  k_tcvt<<<dim3(16, 64), tb, 0, stream>>>(Wv, WT + 2560l * 2048, 2048, 512, 512);
  k_tcvt<<<dim3(64, 64), tb, 0, stream>>>(Wo, WoT, 2048, 2048, 2048);

  k_gemm_qkv<<<dim3(24, 16), 512, 0, stream>>>(xb, WT, Qr, Kr, Vr, fc, fs, 2048);

  k_tvp<<<dim3(16, 64), tb, 0, stream>>>(Vr, Vt);

  k_attn<<<dim3(32, 16), 256, 0, stream>>>(Qr, Kr, Vt, AO);

  k_gemm<<<dim3(16, 16), 512, 0, stream>>>(AO, WoT, out, 2048, 2048, 2048);
}

// Round 11
// 172.051 us; speedup vs baseline: 1.1264x; 1.0137x over previous
//
#include <hip/hip_runtime.h>

#define SEQ 2048
#define DMODEL 2048

typedef __attribute__((ext_vector_type(8))) _Float16 half8;
typedef __attribute__((ext_vector_type(4))) float f32x4;
typedef __attribute__((ext_vector_type(16))) float f32x16;

typedef const __attribute__((address_space(1))) void* gptr_t;
typedef __attribute__((address_space(3))) void* lptr_t;

static __device__ __forceinline__ void gload16(const void* g, void* l) {
  __builtin_amdgcn_global_load_lds((gptr_t)g, (lptr_t)l, 16, 0, 0);
}

static __device__ __forceinline__ unsigned short f2h(float f) {
  _Float16 h = (_Float16)f;
  union { _Float16 h; unsigned short u; } v; v.h = h;
  return v.u;
}

static __device__ __forceinline__ unsigned int pkh2(float a, float b) {
  union { __fp16 __attribute__((ext_vector_type(2))) h; unsigned int u; } v;
  v.h = __builtin_amdgcn_cvt_pkrtz(a, b);
  return v.u;
}

// ---------------- elementwise fp32 -> fp16 ----------------
__global__ void k_cvt(const float* __restrict__ in, unsigned short* __restrict__ out, int n) {
  int i = (blockIdx.x * 256 + threadIdx.x) * 4;
  if (i >= n) return;
  float4 v = *(const float4*)(in + i);
  ushort4 o;
  o.x = f2h(v.x); o.y = f2h(v.y); o.z = f2h(v.z); o.w = f2h(v.w);
  *(ushort4*)(out + i) = o;
}

// ---------------- tiled transpose + convert: in fp32 [K][N] -> out fp16 [N][K] ----------------
__global__ void k_tcvt(const float* __restrict__ in, unsigned short* __restrict__ out,
                       int K, int N, int ldin) {
  __shared__ float tile[32][33];
  int n0 = blockIdx.x * 32, k0 = blockIdx.y * 32;
  int tx = threadIdx.x, ty = threadIdx.y;  // 32 x 8
  #pragma unroll
  for (int j = ty; j < 32; j += 8)
    tile[j][tx] = in[(long)(k0 + j) * ldin + n0 + tx];
  __syncthreads();
  #pragma unroll
  for (int j = ty; j < 32; j += 8)
    out[(long)(n0 + j) * K + k0 + tx] = f2h(tile[tx][j]);
}

// ---------------- V transpose fp16 [S][512] -> Vt [8][64][S] with key permutation ----------------
__global__ void k_tvp(const unsigned short* __restrict__ in, unsigned short* __restrict__ out) {
  __shared__ unsigned short tile[32][33];
  int c0 = blockIdx.x * 32, s0 = blockIdx.y * 32;
  int tx = threadIdx.x, ty = threadIdx.y;  // 32 x 8
  #pragma unroll
  for (int j = ty; j < 32; j += 8)
    tile[j][tx] = in[(long)(s0 + j) * 512 + c0 + tx];
  __syncthreads();
  #pragma unroll
  for (int j = ty; j < 32; j += 8) {
    int c = c0 + j;
    int s = s0 + tx;
    int sp = (s & ~12) | ((s & 8) >> 1) | ((s & 4) << 1);
    out[((long)(c >> 6) * 64 + (c & 63)) * SEQ + sp] = tile[tx][j];
  }
}

// ---------------- GEMM core: 128x128 tile, BK=32, 8 waves (4m x 2n), depth-2 ring ----------------
// LDS tiles XOR-swizzled (T2): 16B-chunk slot c of row r holds global chunk c ^ ((r>>1)&3).
// Write side: linear LDS dest (global_load_lds requirement), pre-swizzled GLOBAL source.
// Read side: same XOR on the chunk index. 8-way bank conflict -> 2-way (free).
static __device__ __forceinline__ void gemm_core(const unsigned short* __restrict__ A,
                                                 const unsigned short* __restrict__ B,
                                                 int K, unsigned short* As, unsigned short* Bs,
                                                 long m0, long n0, int t, int wm, int wn,
                                                 int lr, int lh, f32x4 acc[2][4]) {
  int swc = ((t & 3) ^ ((t >> 3) & 3)) * 8;  // pre-swizzled source chunk for staging row t>>2
  const unsigned short* Ag = A + (m0 + (t >> 2)) * K + swc;
  const unsigned short* Bg = B + (n0 + (t >> 2)) * K + swc;
  #pragma unroll
  for (int i = 0; i < 2; i++)
    #pragma unroll
    for (int j = 0; j < 4; j++)
      acc[i][j] = (f32x4){0.f, 0.f, 0.f, 0.f};

#define STAGE(buf, k0) do { \
    gload16(Ag + (k0), As + (buf) * 4096 + t * 8); \
    gload16(Bg + (k0), Bs + (buf) * 4096 + t * 8); \
  } while (0)

  int T = K >> 5;
  STAGE(0, 0);
  STAGE(1, 32);
  asm volatile("s_waitcnt vmcnt(2)" ::: "memory");
  __builtin_amdgcn_s_barrier();

  int bi = 0;
  for (int ti = 0; ti < T; ti++) {
    if (ti + 2 < T) STAGE((bi + 2) % 3, (ti + 2) * 32);
    const unsigned short* Ab = As + bi * 4096;
    const unsigned short* Bb = Bs + bi * 4096;
    half8 a[2], b[4];
    #pragma unroll
    for (int mf = 0; mf < 2; mf++) {
      int ra = wm * 32 + mf * 16 + lr;
      a[mf] = *(const half8*)&Ab[ra * 32 + ((lh ^ ((ra >> 1) & 3)) * 8)];
    }
    #pragma unroll
    for (int nf = 0; nf < 4; nf++) {
      int rb = wn * 64 + nf * 16 + lr;
      b[nf] = *(const half8*)&Bb[rb * 32 + ((lh ^ ((rb >> 1) & 3)) * 8)];
    }
    #pragma unroll
    for (int mf = 0; mf < 2; mf++)
      #pragma unroll
      for (int nf = 0; nf < 4; nf++)
        acc[mf][nf] = __builtin_amdgcn_mfma_f32_16x16x32_f16(a[mf], b[nf], acc[mf][nf], 0, 0, 0);
    if (ti + 2 < T) asm volatile("s_waitcnt vmcnt(2)" ::: "memory");
    else            asm volatile("s_waitcnt vmcnt(0)" ::: "memory");
    __builtin_amdgcn_s_barrier();
    bi = bi == 2 ? 0 : bi + 1;
  }
#undef STAGE
}

// plain fp32-C GEMM (output projection)
__global__ __launch_bounds__(512) void k_gemm(const unsigned short* __restrict__ A,
                                              const unsigned short* __restrict__ B,
                                              float* __restrict__ C, int M, int N, int K) {
  __shared__ unsigned short As[3 * 4096];
  __shared__ unsigned short Bs[3 * 4096];
  int t = threadIdx.x;
  int l = t & 63, w = t >> 6;
  int wm = w >> 1, wn = w & 1;
  int lr = l & 15, lh = l >> 4;
  long m0 = (long)blockIdx.y * 128, n0 = (long)blockIdx.x * 128;
  f32x4 acc[2][4];
  gemm_core(A, B, K, As, Bs, m0, n0, t, wm, wn, lr, lh, acc);
  #pragma unroll
  for (int mf = 0; mf < 2; mf++)
    #pragma unroll
    for (int nf = 0; nf < 4; nf++)
      #pragma unroll
      for (int i = 0; i < 4; i++)
        C[(m0 + wm * 32 + mf * 16 + lh * 4 + i) * N + n0 + wn * 64 + nf * 16 + lr] = acc[mf][nf][i];
}

// QKV GEMM with fused RoPE + fp16 conversion + layout epilogue.
__global__ __launch_bounds__(512) void k_gemm_qkv(const unsigned short* __restrict__ A,
                                                  const unsigned short* __restrict__ B,
                                                  unsigned short* __restrict__ Qr,
                                                  unsigned short* __restrict__ Kr,
                                                  unsigned short* __restrict__ Vr,
                                                  const float* __restrict__ fc,
                                                  const float* __restrict__ fs, int K) {
  __shared__ unsigned short As[3 * 4096];
  __shared__ unsigned short Bs[3 * 4096];
  int t = threadIdx.x;
  int l = t & 63, w = t >> 6;
  int wm = w >> 1, wn = w & 1;
  int lr = l & 15, lh = l >> 4;
  long m0 = (long)blockIdx.y * 128, n0 = (long)blockIdx.x * 128;
  f32x4 acc[2][4];
  gemm_core(A, B, K, As, Bs, m0, n0, t, wm, wn, lr, lh, acc);

  const float SC = 0.125f * 1.44269504f;
  int n0i = (int)n0;
  if (n0i < 2560) {
    bool isQ = n0i < 2048;
    float scl = isQ ? SC : 1.0f;
    #pragma unroll
    for (int mf = 0; mf < 2; mf++)
      #pragma unroll
      for (int i = 0; i < 4; i++) {
        int row = (int)m0 + wm * 32 + mf * 16 + lh * 4 + i;
        const float* fcr = fc + row * 32;
        const float* fsr = fs + row * 32;
        #pragma unroll
        for (int nf = 0; nf < 4; nf++) {
          float v = acc[mf][nf][i];
          float pv = __shfl_xor(v, 1);
          int col = n0i + wn * 64 + nf * 16 + lr;
          int j = (col & 63) >> 1;
          float c_ = fcr[j] * scl, s_ = fsr[j] * scl;
          float o = (lr & 1) ? (pv * s_ + v * c_) : (v * c_ - pv * s_);
          if (isQ) Qr[(long)row * 2048 + col] = f2h(o);
          else {
            int cc = col - 2048;
            Kr[((long)(cc >> 6) * SEQ + row) * 64 + (cc & 63)] = f2h(o);
          }
        }
      }
  } else {
    #pragma unroll
    for (int mf = 0; mf < 2; mf++)
      #pragma unroll
      for (int i = 0; i < 4; i++) {
        int row = (int)m0 + wm * 32 + mf * 16 + lh * 4 + i;
        #pragma unroll
        for (int nf = 0; nf < 4; nf++) {
          int col = n0i + wn * 64 + nf * 16 + lr;
          Vr[(long)row * 512 + (col - 2560)] = f2h(acc[mf][nf][i]);
        }
      }
  }
}

// ---------------- causal GQA flash attention: KVBLK=128 super-tiles, double-buffered LDS ----------------
__global__ __launch_bounds__(256) void k_attn(const unsigned short* __restrict__ Qr,
                                              const unsigned short* __restrict__ Kr,
                                              const unsigned short* __restrict__ Vg,
                                              unsigned short* __restrict__ AO) {
  __shared__ unsigned short KT[2][8192];  // 2 x [4 subtiles][32 keys][64 d] swizzled
  __shared__ unsigned short VT[2][8192];  // 2 x [4 subtiles][64 d][32 keys] swizzled
  __shared__ float gbuf[4][32];

  int tt = threadIdx.x;
  int wid = tt >> 6, l = tt & 63;
  int q = l & 31, hs = l >> 5;
  int h = blockIdx.x, hkv = h >> 2;
  int by = (int)gridDim.y - 1 - blockIdx.y;  // longest blocks dispatch first
  int dt = 4 * by + wid;                     // this wave's diagonal kv-tile
  int q0 = by * 128 + wid * 32;

  const unsigned short* Kh = Kr + (long)hkv * SEQ * 64;
  const unsigned short* Vh = Vg + (long)hkv * 64 * SEQ;

  // staging source addresses (pre-swizzled global so LDS dest stays linear)
  int skr = tt >> 3, skc = tt & 7;  // K: row (key), 16B-chunk
  int svr = tt >> 2, svc = tt & 3;  // V: row (d), 16B-chunk
  const unsigned short* Ksrc = Kh + (long)skr * 64 + ((skc * 8) ^ ((skr & 7) << 3));
  const unsigned short* Vsrc = Vh + (long)svr * SEQ + ((svc * 8) ^ ((svr & 3) << 3));

#define ASTAGE(si) do { \
    int buf_ = (si) & 1; \
    _Pragma("unroll") for (int sub_ = 0; sub_ < 4; sub_++) { \
      int t0_ = ((si) * 4 + sub_) * 32; \
      gload16(Ksrc + (long)t0_ * 64, &KT[buf_][sub_ * 2048 + tt * 8]); \
      gload16(Vsrc + t0_, &VT[buf_][sub_ * 2048 + tt * 8]); \
    } \
  } while (0)

  // Q fragments (B-operand of swapped QK^T), hoisted
  half8 Qf[4];
  #pragma unroll
  for (int d = 0; d < 4; d++)
    Qf[d] = *(const half8*)&Qr[(long)(q0 + q) * 2048 + h * 64 + d * 16 + 8 * hs];

  f32x16 O0, O1;
  #pragma unroll
  for (int r = 0; r < 16; r++) { O0[r] = 0.f; O1[r] = 0.f; }
  float lsum = 0.f;

  ASTAGE(0);
  asm volatile("s_waitcnt vmcnt(0)" ::: "memory");
  __builtin_amdgcn_s_barrier();

  for (int si = 0; si <= by; si++) {
    if (si + 1 <= by) ASTAGE(si + 1);  // issue next super early; drained at end of this one

    int buf = si & 1;
    #pragma unroll
    for (int sub = 0; sub < 4; sub++) {
      int ti = si * 4 + sub;
      if (ti <= dt) {
        const unsigned short* Ks = &KT[buf][sub * 2048];
        const unsigned short* Vs = &VT[buf][sub * 2048];
        half8 Kf[4], Vf[2][2];
        #pragma unroll
        for (int d = 0; d < 4; d++) {
          int e0 = d * 16 + 8 * hs;
          Kf[d] = *(const half8*)&Ks[q * 64 + (e0 ^ ((q & 7) << 3))];
        }
        #pragma unroll
        for (int ks = 0; ks < 2; ks++)
          #pragma unroll
          for (int nf = 0; nf < 2; nf++) {
            int d = q + 32 * nf;
            int e0 = ks * 16 + 8 * hs;
            Vf[ks][nf] = *(const half8*)&Vs[d * 32 + (e0 ^ ((d & 3) << 3))];
          }

        f32x16 S;
        #pragma unroll
        for (int r = 0; r < 16; r++) S[r] = 0.f;
        #pragma unroll
        for (int d = 0; d < 4; d++)
          S = __builtin_amdgcn_mfma_f32_32x32x16_f16(Kf[d], Qf[d], S, 0, 0, 0);

        bool dg = (ti == dt);
        float p[16];
        #pragma unroll
        for (int r = 0; r < 16; r++) {
          float v = S[r];
          if (dg) {
            int key = (r & 3) + 8 * (r >> 2) + 4 * hs;
            if (key > q) v = -1e30f;
          }
          p[r] = __builtin_exp2f(v - 8.0f);
          lsum += p[r];
        }

        union { unsigned int u[4]; half8 hh; } f0, f1;
        #pragma unroll
        for (int c = 0; c < 4; c++) {
          f0.u[c] = pkh2(p[2 * c], p[2 * c + 1]);
          f1.u[c] = pkh2(p[8 + 2 * c], p[9 + 2 * c]);
        }

        O0 = __builtin_amdgcn_mfma_f32_32x32x16_f16(f0.hh, Vf[0][0], O0, 0, 0, 0);
        O0 = __builtin_amdgcn_mfma_f32_32x32x16_f16(f1.hh, Vf[1][0], O0, 0, 0, 0);
        O1 = __builtin_amdgcn_mfma_f32_32x32x16_f16(f0.hh, Vf[0][1], O1, 0, 0, 0);
        O1 = __builtin_amdgcn_mfma_f32_32x32x16_f16(f1.hh, Vf[1][1], O1, 0, 0, 0);
      }
    }

    asm volatile("s_waitcnt vmcnt(0)" ::: "memory");  // next super's loads: issued ~4 subtiles ago
    __builtin_amdgcn_s_barrier();
  }
#undef ASTAGE

  // per-wave normalization (no cross-wave merge)
  lsum += __shfl_xor(lsum, 32);
  if (l < 32) gbuf[wid][l] = 1.f / lsum;
  asm volatile("" ::: "memory");
  #pragma unroll
  for (int r = 0; r < 16; r++) {
    int row = (r & 3) + 8 * (r >> 2) + 4 * hs;
    float ri = gbuf[wid][row];
    AO[(long)(q0 + row) * 2048 + h * 64 + q] = f2h(O0[r] * ri);
    AO[(long)(q0 + row) * 2048 + h * 64 + q + 32] = f2h(O1[r] * ri);
  }
}

extern "C" void kernel_launch(void* const* d_in, const int* in_sizes, int n_in,
                              void* d_out, int out_size, void* d_ws, size_t ws_size,
                              hipStream_t stream) {
  const float* x  = (const float*)d_in[0];
  const float* fc = (const float*)d_in[1];
  const float* fs = (const float*)d_in[2];
  const float* Wq = (const float*)d_in[4];
  const float* Wk = (const float*)d_in[5];
  const float* Wv = (const float*)d_in[6];
  const float* Wo = (const float*)d_in[7];
  float* out = (float*)d_out;

  char* ws = (char*)d_ws;
  unsigned short* xb  = (unsigned short*)(ws);                  // 8 MB (reused as AO later)
  unsigned short* WT  = (unsigned short*)(ws + (8l  << 20));    // 12 MB  [3072][2048] fp16
  unsigned short* WoT = (unsigned short*)(ws + (20l << 20));    // 8 MB   [2048][2048] fp16
  unsigned short* Qr  = (unsigned short*)(ws + (28l << 20));    // 8 MB   [S][2048] fp16
  unsigned short* Kr  = (unsigned short*)(ws + (36l << 20));    // 2 MB   [8][S][64] fp16
  unsigned short* Vr  = (unsigned short*)(ws + (38l << 20));    // 2 MB   [S][512] fp16
  unsigned short* Vt  = (unsigned short*)(ws + (40l << 20));    // 2 MB   [8][64][S] fp16 (key-permuted)
  unsigned short* AO  = xb;                                     // overlay: xb dead after QKV GEMM

  dim3 tb(32, 8);
  k_cvt<<<4096, 256, 0, stream>>>(x, xb, 2048 * 2048);
  k_tcvt<<<dim3(64, 64), tb, 0, stream>>>(Wq, WT, 2048, 2048, 2048);
  k_tcvt<<<dim3(16, 64), tb, 0, stream>>>(Wk, WT + 2048l * 2048, 2048, 512, 512);
  k_tcvt<<<dim3(16, 64), tb, 0, stream>>>(Wv, WT + 2560l * 2048, 2048, 512, 512);
  k_tcvt<<<dim3(64, 64), tb, 0, stream>>>(Wo, WoT, 2048, 2048, 2048);

  k_gemm_qkv<<<dim3(24, 16), 512, 0, stream>>>(xb, WT, Qr, Kr, Vr, fc, fs, 2048);

  k_tvp<<<dim3(16, 64), tb, 0, stream>>>(Vr, Vt);

  k_attn<<<dim3(32, 16), 256, 0, stream>>>(Qr, Kr, Vt, AO);

  k_gemm<<<dim3(16, 16), 512, 0, stream>>>(AO, WoT, out, 2048, 2048, 2048);
}

// Round 12
// 156.860 us; speedup vs baseline: 1.2355x; 1.0968x over previous
//
#include <hip/hip_runtime.h>

#define SEQ 2048
#define DMODEL 2048

typedef __attribute__((ext_vector_type(8))) _Float16 half8;
typedef __attribute__((ext_vector_type(4))) float f32x4;
typedef __attribute__((ext_vector_type(16))) float f32x16;

typedef const __attribute__((address_space(1))) void* gptr_t;
typedef __attribute__((address_space(3))) void* lptr_t;

static __device__ __forceinline__ void gload16(const void* g, void* l) {
  __builtin_amdgcn_global_load_lds((gptr_t)g, (lptr_t)l, 16, 0, 0);
}

static __device__ __forceinline__ unsigned short f2h(float f) {
  _Float16 h = (_Float16)f;
  union { _Float16 h; unsigned short u; } v; v.h = h;
  return v.u;
}

static __device__ __forceinline__ unsigned int pkh2(float a, float b) {
  union { __fp16 __attribute__((ext_vector_type(2))) h; unsigned int u; } v;
  v.h = __builtin_amdgcn_cvt_pkrtz(a, b);
  return v.u;
}

// ---------------- elementwise fp32 -> fp16 ----------------
__global__ void k_cvt(const float* __restrict__ in, unsigned short* __restrict__ out, int n) {
  int i = (blockIdx.x * 256 + threadIdx.x) * 4;
  if (i >= n) return;
  float4 v = *(const float4*)(in + i);
  ushort4 o;
  o.x = f2h(v.x); o.y = f2h(v.y); o.z = f2h(v.z); o.w = f2h(v.w);
  *(ushort4*)(out + i) = o;
}

// ---------------- tiled transpose + convert: in fp32 [K][N] -> out fp16 [N][K] ----------------
__global__ void k_tcvt(const float* __restrict__ in, unsigned short* __restrict__ out,
                       int K, int N, int ldin) {
  __shared__ float tile[32][33];
  int n0 = blockIdx.x * 32, k0 = blockIdx.y * 32;
  int tx = threadIdx.x, ty = threadIdx.y;  // 32 x 8
  #pragma unroll
  for (int j = ty; j < 32; j += 8)
    tile[j][tx] = in[(long)(k0 + j) * ldin + n0 + tx];
  __syncthreads();
  #pragma unroll
  for (int j = ty; j < 32; j += 8)
    out[(long)(n0 + j) * K + k0 + tx] = f2h(tile[tx][j]);
}

// ---------------- V transpose fp16 [S][512] -> Vt [8][64][S] with key permutation ----------------
__global__ void k_tvp(const unsigned short* __restrict__ in, unsigned short* __restrict__ out) {
  __shared__ unsigned short tile[32][33];
  int c0 = blockIdx.x * 32, s0 = blockIdx.y * 32;
  int tx = threadIdx.x, ty = threadIdx.y;  // 32 x 8
  #pragma unroll
  for (int j = ty; j < 32; j += 8)
    tile[j][tx] = in[(long)(s0 + j) * 512 + c0 + tx];
  __syncthreads();
  #pragma unroll
  for (int j = ty; j < 32; j += 8) {
    int c = c0 + j;
    int s = s0 + tx;
    int sp = (s & ~12) | ((s & 8) >> 1) | ((s & 4) << 1);
    out[((long)(c >> 6) * 64 + (c & 63)) * SEQ + sp] = tile[tx][j];
  }
}

// ---------------- GEMM core v2: 128x128 tile, BK=64, 8 waves = 2m x 2n x 2k-split ----------------
// Each wave: 64x64 output over its K-half (4x4 16x16x32 frags) -> 32 FLOP per LDS byte (vs 21).
// LDS 64KB: 2 x (A 16KB + B 16KB), stage-1-ahead. Tiles row-major [128][64] with 16B-chunk
// XOR swizzle slot = chunk ^ (row&7) (write side: linear LDS dest + pre-swizzled global source).
// After the K loop, ks=1 waves dump acc to LDS; ks=0 waves reduce. Returns true for ks==0.
static __device__ __forceinline__ bool gemm_core(const unsigned short* __restrict__ A,
                                                 const unsigned short* __restrict__ B,
                                                 int K, char* SM, long m0, long n0,
                                                 int& wmO, int& wnO, f32x4 acc[4][4]) {
  int t = threadIdx.x;
  int l = t & 63, w = t >> 6;
  int ks = w & 1, wm = (w >> 2) & 1, wn = (w >> 1) & 1;
  int lr = l & 15, lh = l >> 4;
  wmO = wm; wnO = wn;
  unsigned short* As = (unsigned short*)SM;            // 2 x 8192 shorts
  unsigned short* Bs = (unsigned short*)(SM + 32768);  // 2 x 8192 shorts

  // staging: thread t handles rows t>>3 and (t>>3)+64, chunk slot t&7 -> global chunk (t&7)^((t>>3)&7)
  const unsigned short* Ag = A + (m0 + (t >> 3)) * K + (((t & 7) ^ ((t >> 3) & 7)) * 8);
  const unsigned short* Bg = B + (n0 + (t >> 3)) * K + (((t & 7) ^ ((t >> 3) & 7)) * 8);

  #pragma unroll
  for (int i = 0; i < 4; i++)
    #pragma unroll
    for (int j = 0; j < 4; j++)
      acc[i][j] = (f32x4){0.f, 0.f, 0.f, 0.f};

#define STG(buf, k0) do { \
    gload16(Ag + (k0), As + (buf) * 8192 + t * 8); \
    gload16(Ag + 64 * K + (k0), As + (buf) * 8192 + 4096 + t * 8); \
    gload16(Bg + (k0), Bs + (buf) * 8192 + t * 8); \
    gload16(Bg + 64 * K + (k0), Bs + (buf) * 8192 + 4096 + t * 8); \
  } while (0)

  int T = K >> 6;  // phases of BK=64
  STG(0, 0);
  asm volatile("s_waitcnt vmcnt(0)" ::: "memory");
  __builtin_amdgcn_s_barrier();

  for (int ph = 0; ph < T; ph++) {
    if (ph + 1 < T) STG((ph + 1) & 1, (ph + 1) * 64);  // issue early, overlaps this phase's compute
    const unsigned short* Ab = As + (ph & 1) * 8192;
    const unsigned short* Bb = Bs + (ph & 1) * 8192;
    half8 a[4], b[4];
    #pragma unroll
    for (int mf = 0; mf < 4; mf++) {
      int ra = wm * 64 + mf * 16 + lr;
      a[mf] = *(const half8*)&Ab[ra * 64 + (((ks * 4 + lh) ^ (ra & 7)) * 8)];
    }
    #pragma unroll
    for (int nf = 0; nf < 4; nf++) {
      int rb = wn * 64 + nf * 16 + lr;
      b[nf] = *(const half8*)&Bb[rb * 64 + (((ks * 4 + lh) ^ (rb & 7)) * 8)];
    }
    #pragma unroll
    for (int mf = 0; mf < 4; mf++)
      #pragma unroll
      for (int nf = 0; nf < 4; nf++)
        acc[mf][nf] = __builtin_amdgcn_mfma_f32_16x16x32_f16(a[mf], b[nf], acc[mf][nf], 0, 0, 0);
    asm volatile("s_waitcnt vmcnt(0)" ::: "memory");
    __builtin_amdgcn_s_barrier();
  }
#undef STG

  // ---- split-K reduction: ks=1 -> LDS -> ks=0 adds ----
  __syncthreads();
  float* red = (float*)SM;  // 16K floats = 64KB, overlays As/Bs
  int p = wm * 2 + wn;
  if (ks == 1) {
    #pragma unroll
    for (int mf = 0; mf < 4; mf++)
      #pragma unroll
      for (int nf = 0; nf < 4; nf++)
        *(f32x4*)&red[p * 4096 + l * 64 + (((mf * 4 + nf) ^ (l & 15)) << 2)] = acc[mf][nf];
  }
  __syncthreads();
  if (ks == 0) {
    #pragma unroll
    for (int mf = 0; mf < 4; mf++)
      #pragma unroll
      for (int nf = 0; nf < 4; nf++)
        acc[mf][nf] += *(const f32x4*)&red[p * 4096 + l * 64 + (((mf * 4 + nf) ^ (l & 15)) << 2)];
  }
  return ks == 0;
}

// plain fp32-C GEMM (output projection)
__global__ __launch_bounds__(512) void k_gemm(const unsigned short* __restrict__ A,
                                              const unsigned short* __restrict__ B,
                                              float* __restrict__ C, int M, int N, int K) {
  __shared__ __align__(16) char SM[65536];
  int l = threadIdx.x & 63;
  int lr = l & 15, lh = l >> 4;
  long m0 = (long)blockIdx.y * 128, n0 = (long)blockIdx.x * 128;
  f32x4 acc[4][4];
  int wm, wn;
  bool own = gemm_core(A, B, K, SM, m0, n0, wm, wn, acc);
  if (own) {
    #pragma unroll
    for (int mf = 0; mf < 4; mf++)
      #pragma unroll
      for (int nf = 0; nf < 4; nf++)
        #pragma unroll
        for (int i = 0; i < 4; i++)
          C[(m0 + wm * 64 + mf * 16 + lh * 4 + i) * N + n0 + wn * 64 + nf * 16 + lr] = acc[mf][nf][i];
  }
}

// QKV GEMM with fused RoPE + fp16 conversion + layout epilogue.
__global__ __launch_bounds__(512) void k_gemm_qkv(const unsigned short* __restrict__ A,
                                                  const unsigned short* __restrict__ B,
                                                  unsigned short* __restrict__ Qr,
                                                  unsigned short* __restrict__ Kr,
                                                  unsigned short* __restrict__ Vr,
                                                  const float* __restrict__ fc,
                                                  const float* __restrict__ fs, int K) {
  __shared__ __align__(16) char SM[65536];
  int l = threadIdx.x & 63;
  int lr = l & 15, lh = l >> 4;
  long m0 = (long)blockIdx.y * 128, n0 = (long)blockIdx.x * 128;
  f32x4 acc[4][4];
  int wm, wn;
  bool own = gemm_core(A, B, K, SM, m0, n0, wm, wn, acc);
  if (!own) return;

  const float SC = 0.125f * 1.44269504f;
  int n0i = (int)n0;
  if (n0i < 2560) {
    bool isQ = n0i < 2048;
    float scl = isQ ? SC : 1.0f;
    #pragma unroll
    for (int mf = 0; mf < 4; mf++)
      #pragma unroll
      for (int i = 0; i < 4; i++) {
        int row = (int)m0 + wm * 64 + mf * 16 + lh * 4 + i;
        const float* fcr = fc + row * 32;
        const float* fsr = fs + row * 32;
        #pragma unroll
        for (int nf = 0; nf < 4; nf++) {
          float v = acc[mf][nf][i];
          float pv = __shfl_xor(v, 1);
          int col = n0i + wn * 64 + nf * 16 + lr;
          int j = (col & 63) >> 1;
          float c_ = fcr[j] * scl, s_ = fsr[j] * scl;
          float o = (lr & 1) ? (pv * s_ + v * c_) : (v * c_ - pv * s_);
          if (isQ) Qr[(long)row * 2048 + col] = f2h(o);
          else {
            int cc = col - 2048;
            Kr[((long)(cc >> 6) * SEQ + row) * 64 + (cc & 63)] = f2h(o);
          }
        }
      }
  } else {
    #pragma unroll
    for (int mf = 0; mf < 4; mf++)
      #pragma unroll
      for (int i = 0; i < 4; i++) {
        int row = (int)m0 + wm * 64 + mf * 16 + lh * 4 + i;
        #pragma unroll
        for (int nf = 0; nf < 4; nf++) {
          int col = n0i + wn * 64 + nf * 16 + lr;
          Vr[(long)row * 512 + (col - 2560)] = f2h(acc[mf][nf][i]);
        }
      }
  }
}

// ---------------- causal GQA flash attention: KVBLK=128 super-tiles, double-buffered LDS ----------------
__global__ __launch_bounds__(256) void k_attn(const unsigned short* __restrict__ Qr,
                                              const unsigned short* __restrict__ Kr,
                                              const unsigned short* __restrict__ Vg,
                                              unsigned short* __restrict__ AO) {
  __shared__ unsigned short KT[2][8192];  // 2 x [4 subtiles][32 keys][64 d] swizzled
  __shared__ unsigned short VT[2][8192];  // 2 x [4 subtiles][64 d][32 keys] swizzled
  __shared__ float gbuf[4][32];

  int tt = threadIdx.x;
  int wid = tt >> 6, l = tt & 63;
  int q = l & 31, hs = l >> 5;
  int h = blockIdx.x, hkv = h >> 2;
  int by = (int)gridDim.y - 1 - blockIdx.y;  // longest blocks dispatch first
  int dt = 4 * by + wid;                     // this wave's diagonal kv-tile
  int q0 = by * 128 + wid * 32;

  const unsigned short* Kh = Kr + (long)hkv * SEQ * 64;
  const unsigned short* Vh = Vg + (long)hkv * 64 * SEQ;

  // staging source addresses (pre-swizzled global so LDS dest stays linear)
  int skr = tt >> 3, skc = tt & 7;  // K: row (key), 16B-chunk
  int svr = tt >> 2, svc = tt & 3;  // V: row (d), 16B-chunk
  const unsigned short* Ksrc = Kh + (long)skr * 64 + ((skc * 8) ^ ((skr & 7) << 3));
  const unsigned short* Vsrc = Vh + (long)svr * SEQ + ((svc * 8) ^ ((svr & 3) << 3));

#define ASTAGE(si) do { \
    int buf_ = (si) & 1; \
    _Pragma("unroll") for (int sub_ = 0; sub_ < 4; sub_++) { \
      int t0_ = ((si) * 4 + sub_) * 32; \
      gload16(Ksrc + (long)t0_ * 64, &KT[buf_][sub_ * 2048 + tt * 8]); \
      gload16(Vsrc + t0_, &VT[buf_][sub_ * 2048 + tt * 8]); \
    } \
  } while (0)

  // Q fragments (B-operand of swapped QK^T), hoisted
  half8 Qf[4];
  #pragma unroll
  for (int d = 0; d < 4; d++)
    Qf[d] = *(const half8*)&Qr[(long)(q0 + q) * 2048 + h * 64 + d * 16 + 8 * hs];

  f32x16 O0, O1;
  #pragma unroll
  for (int r = 0; r < 16; r++) { O0[r] = 0.f; O1[r] = 0.f; }
  float lsum = 0.f;

  ASTAGE(0);
  asm volatile("s_waitcnt vmcnt(0)" ::: "memory");
  __builtin_amdgcn_s_barrier();

  for (int si = 0; si <= by; si++) {
    if (si + 1 <= by) ASTAGE(si + 1);  // issue next super early; drained at end of this one

    int buf = si & 1;
    #pragma unroll
    for (int sub = 0; sub < 4; sub++) {
      int ti = si * 4 + sub;
      if (ti <= dt) {
        const unsigned short* Ks = &KT[buf][sub * 2048];
        const unsigned short* Vs = &VT[buf][sub * 2048];
        half8 Kf[4], Vf[2][2];
        #pragma unroll
        for (int d = 0; d < 4; d++) {
          int e0 = d * 16 + 8 * hs;
          Kf[d] = *(const half8*)&Ks[q * 64 + (e0 ^ ((q & 7) << 3))];
        }
        #pragma unroll
        for (int ks = 0; ks < 2; ks++)
          #pragma unroll
          for (int nf = 0; nf < 2; nf++) {
            int d = q + 32 * nf;
            int e0 = ks * 16 + 8 * hs;
            Vf[ks][nf] = *(const half8*)&Vs[d * 32 + (e0 ^ ((d & 3) << 3))];
          }

        f32x16 S;
        #pragma unroll
        for (int r = 0; r < 16; r++) S[r] = 0.f;
        #pragma unroll
        for (int d = 0; d < 4; d++)
          S = __builtin_amdgcn_mfma_f32_32x32x16_f16(Kf[d], Qf[d], S, 0, 0, 0);

        bool dg = (ti == dt);
        float p[16];
        #pragma unroll
        for (int r = 0; r < 16; r++) {
          float v = S[r];
          if (dg) {
            int key = (r & 3) + 8 * (r >> 2) + 4 * hs;
            if (key > q) v = -1e30f;
          }
          p[r] = __builtin_exp2f(v - 8.0f);
          lsum += p[r];
        }

        union { unsigned int u[4]; half8 hh; } f0, f1;
        #pragma unroll
        for (int c = 0; c < 4; c++) {
          f0.u[c] = pkh2(p[2 * c], p[2 * c + 1]);
          f1.u[c] = pkh2(p[8 + 2 * c], p[9 + 2 * c]);
        }

        O0 = __builtin_amdgcn_mfma_f32_32x32x16_f16(f0.hh, Vf[0][0], O0, 0, 0, 0);
        O0 = __builtin_amdgcn_mfma_f32_32x32x16_f16(f1.hh, Vf[1][0], O0, 0, 0, 0);
        O1 = __builtin_amdgcn_mfma_f32_32x32x16_f16(f0.hh, Vf[0][1], O1, 0, 0, 0);
        O1 = __builtin_amdgcn_mfma_f32_32x32x16_f16(f1.hh, Vf[1][1], O1, 0, 0, 0);
      }
    }

    asm volatile("s_waitcnt vmcnt(0)" ::: "memory");  // next super's loads: issued ~4 subtiles ago
    __builtin_amdgcn_s_barrier();
  }
#undef ASTAGE

  // per-wave normalization (no cross-wave merge)
  lsum += __shfl_xor(lsum, 32);
  if (l < 32) gbuf[wid][l] = 1.f / lsum;
  asm volatile("" ::: "memory");
  #pragma unroll
  for (int r = 0; r < 16; r++) {
    int row = (r & 3) + 8 * (r >> 2) + 4 * hs;
    float ri = gbuf[wid][row];
    AO[(long)(q0 + row) * 2048 + h * 64 + q] = f2h(O0[r] * ri);
    AO[(long)(q0 + row) * 2048 + h * 64 + q + 32] = f2h(O1[r] * ri);
  }
}

extern "C" void kernel_launch(void* const* d_in, const int* in_sizes, int n_in,
                              void* d_out, int out_size, void* d_ws, size_t ws_size,
                              hipStream_t stream) {
  const float* x  = (const float*)d_in[0];
  const float* fc = (const float*)d_in[1];
  const float* fs = (const float*)d_in[2];
  const float* Wq = (const float*)d_in[4];
  const float* Wk = (const float*)d_in[5];
  const float* Wv = (const float*)d_in[6];
  const float* Wo = (const float*)d_in[7];
  float* out = (float*)d_out;

  char* ws = (char*)d_ws;
  unsigned short* xb  = (unsigned short*)(ws);                  // 8 MB (reused as AO later)
  unsigned short* WT  = (unsigned short*)(ws + (8l  << 20));    // 12 MB  [3072][2048] fp16
  unsigned short* WoT = (unsigned short*)(ws + (20l << 20));    // 8 MB   [2048][2048] fp16
  unsigned short* Qr  = (unsigned short*)(ws + (28l << 20));    // 8 MB   [S][2048] fp16
  unsigned short* Kr  = (unsigned short*)(ws + (36l << 20));    // 2 MB   [8][S][64] fp16
  unsigned short* Vr  = (unsigned short*)(ws + (38l << 20));    // 2 MB   [S][512] fp16
  unsigned short* Vt  = (unsigned short*)(ws + (40l << 20));    // 2 MB   [8][64][S] fp16 (key-permuted)
  unsigned short* AO  = xb;                                     // overlay: xb dead after QKV GEMM

  dim3 tb(32, 8);
  k_cvt<<<4096, 256, 0, stream>>>(x, xb, 2048 * 2048);
  k_tcvt<<<dim3(64, 64), tb, 0, stream>>>(Wq, WT, 2048, 2048, 2048);
  k_tcvt<<<dim3(16, 64), tb, 0, stream>>>(Wk, WT + 2048l * 2048, 2048, 512, 512);
  k_tcvt<<<dim3(16, 64), tb, 0, stream>>>(Wv, WT + 2560l * 2048, 2048, 512, 512);
  k_tcvt<<<dim3(64, 64), tb, 0, stream>>>(Wo, WoT, 2048, 2048, 2048);

  k_gemm_qkv<<<dim3(24, 16), 512, 0, stream>>>(xb, WT, Qr, Kr, Vr, fc, fs, 2048);

  k_tvp<<<dim3(16, 64), tb, 0, stream>>>(Vr, Vt);

  k_attn<<<dim3(32, 16), 256, 0, stream>>>(Qr, Kr, Vt, AO);

  k_gemm<<<dim3(16, 16), 512, 0, stream>>>(AO, WoT, out, 2048, 2048, 2048);
}

// Round 13
// 155.706 us; speedup vs baseline: 1.2447x; 1.0074x over previous
//
#include <hip/hip_runtime.h>

#define SEQ 2048
#define DMODEL 2048

typedef __attribute__((ext_vector_type(8))) _Float16 half8;
typedef __attribute__((ext_vector_type(4))) float f32x4;
typedef __attribute__((ext_vector_type(16))) float f32x16;

typedef const __attribute__((address_space(1))) void* gptr_t;
typedef __attribute__((address_space(3))) void* lptr_t;

static __device__ __forceinline__ void gload16(const void* g, void* l) {
  __builtin_amdgcn_global_load_lds((gptr_t)g, (lptr_t)l, 16, 0, 0);
}

static __device__ __forceinline__ unsigned short f2h(float f) {
  _Float16 h = (_Float16)f;
  union { _Float16 h; unsigned short u; } v; v.h = h;
  return v.u;
}

static __device__ __forceinline__ unsigned int pkh2(float a, float b) {
  union { __fp16 __attribute__((ext_vector_type(2))) h; unsigned int u; } v;
  v.h = __builtin_amdgcn_cvt_pkrtz(a, b);
  return v.u;
}

// ---------------- elementwise fp32 -> fp16 ----------------
__global__ void k_cvt(const float* __restrict__ in, unsigned short* __restrict__ out, int n) {
  int i = (blockIdx.x * 256 + threadIdx.x) * 4;
  if (i >= n) return;
  float4 v = *(const float4*)(in + i);
  ushort4 o;
  o.x = f2h(v.x); o.y = f2h(v.y); o.z = f2h(v.z); o.w = f2h(v.w);
  *(ushort4*)(out + i) = o;
}

// ---------------- tiled transpose + convert: in fp32 [K][N] -> out fp16 [N][K] ----------------
__global__ void k_tcvt(const float* __restrict__ in, unsigned short* __restrict__ out,
                       int K, int N, int ldin) {
  __shared__ float tile[32][33];
  int n0 = blockIdx.x * 32, k0 = blockIdx.y * 32;
  int tx = threadIdx.x, ty = threadIdx.y;  // 32 x 8
  #pragma unroll
  for (int j = ty; j < 32; j += 8)
    tile[j][tx] = in[(long)(k0 + j) * ldin + n0 + tx];
  __syncthreads();
  #pragma unroll
  for (int j = ty; j < 32; j += 8)
    out[(long)(n0 + j) * K + k0 + tx] = f2h(tile[tx][j]);
}

// ---------------- V transpose fp16 [S][512] -> Vt [8][64][S] with key permutation ----------------
__global__ void k_tvp(const unsigned short* __restrict__ in, unsigned short* __restrict__ out) {
  __shared__ unsigned short tile[32][33];
  int c0 = blockIdx.x * 32, s0 = blockIdx.y * 32;
  int tx = threadIdx.x, ty = threadIdx.y;  // 32 x 8
  #pragma unroll
  for (int j = ty; j < 32; j += 8)
    tile[j][tx] = in[(long)(s0 + j) * 512 + c0 + tx];
  __syncthreads();
  #pragma unroll
  for (int j = ty; j < 32; j += 8) {
    int c = c0 + j;
    int s = s0 + tx;
    int sp = (s & ~12) | ((s & 8) >> 1) | ((s & 4) << 1);
    out[((long)(c >> 6) * 64 + (c & 63)) * SEQ + sp] = tile[tx][j];
  }
}

// ---------------- GEMM core v2: 128x128 tile, BK=64, 8 waves = 2m x 2n x 2k-split ----------------
static __device__ __forceinline__ bool gemm_core(const unsigned short* __restrict__ A,
                                                 const unsigned short* __restrict__ B,
                                                 int K, char* SM, long m0, long n0,
                                                 int& wmO, int& wnO, f32x4 acc[4][4]) {
  int t = threadIdx.x;
  int l = t & 63, w = t >> 6;
  int ks = w & 1, wm = (w >> 2) & 1, wn = (w >> 1) & 1;
  int lr = l & 15, lh = l >> 4;
  wmO = wm; wnO = wn;
  unsigned short* As = (unsigned short*)SM;            // 2 x 8192 shorts
  unsigned short* Bs = (unsigned short*)(SM + 32768);  // 2 x 8192 shorts

  const unsigned short* Ag = A + (m0 + (t >> 3)) * K + (((t & 7) ^ ((t >> 3) & 7)) * 8);
  const unsigned short* Bg = B + (n0 + (t >> 3)) * K + (((t & 7) ^ ((t >> 3) & 7)) * 8);

  #pragma unroll
  for (int i = 0; i < 4; i++)
    #pragma unroll
    for (int j = 0; j < 4; j++)
      acc[i][j] = (f32x4){0.f, 0.f, 0.f, 0.f};

#define STG(buf, k0) do { \
    gload16(Ag + (k0), As + (buf) * 8192 + t * 8); \
    gload16(Ag + 64 * K + (k0), As + (buf) * 8192 + 4096 + t * 8); \
    gload16(Bg + (k0), Bs + (buf) * 8192 + t * 8); \
    gload16(Bg + 64 * K + (k0), Bs + (buf) * 8192 + 4096 + t * 8); \
  } while (0)

  int T = K >> 6;  // phases of BK=64
  STG(0, 0);
  asm volatile("s_waitcnt vmcnt(0)" ::: "memory");
  __builtin_amdgcn_s_barrier();

  for (int ph = 0; ph < T; ph++) {
    if (ph + 1 < T) STG((ph + 1) & 1, (ph + 1) * 64);
    const unsigned short* Ab = As + (ph & 1) * 8192;
    const unsigned short* Bb = Bs + (ph & 1) * 8192;
    half8 a[4], b[4];
    #pragma unroll
    for (int mf = 0; mf < 4; mf++) {
      int ra = wm * 64 + mf * 16 + lr;
      a[mf] = *(const half8*)&Ab[ra * 64 + (((ks * 4 + lh) ^ (ra & 7)) * 8)];
    }
    #pragma unroll
    for (int nf = 0; nf < 4; nf++) {
      int rb = wn * 64 + nf * 16 + lr;
      b[nf] = *(const half8*)&Bb[rb * 64 + (((ks * 4 + lh) ^ (rb & 7)) * 8)];
    }
    #pragma unroll
    for (int mf = 0; mf < 4; mf++)
      #pragma unroll
      for (int nf = 0; nf < 4; nf++)
        acc[mf][nf] = __builtin_amdgcn_mfma_f32_16x16x32_f16(a[mf], b[nf], acc[mf][nf], 0, 0, 0);
    asm volatile("s_waitcnt vmcnt(0)" ::: "memory");
    __builtin_amdgcn_s_barrier();
  }
#undef STG

  // ---- split-K reduction: ks=1 -> LDS -> ks=0 adds ----
  __syncthreads();
  float* red = (float*)SM;
  int p = wm * 2 + wn;
  if (ks == 1) {
    #pragma unroll
    for (int mf = 0; mf < 4; mf++)
      #pragma unroll
      for (int nf = 0; nf < 4; nf++)
        *(f32x4*)&red[p * 4096 + l * 64 + (((mf * 4 + nf) ^ (l & 15)) << 2)] = acc[mf][nf];
  }
  __syncthreads();
  if (ks == 0) {
    #pragma unroll
    for (int mf = 0; mf < 4; mf++)
      #pragma unroll
      for (int nf = 0; nf < 4; nf++)
        acc[mf][nf] += *(const f32x4*)&red[p * 4096 + l * 64 + (((mf * 4 + nf) ^ (l & 15)) << 2)];
  }
  return ks == 0;
}

// plain fp32-C GEMM (output projection)
__global__ __launch_bounds__(512) void k_gemm(const unsigned short* __restrict__ A,
                                              const unsigned short* __restrict__ B,
                                              float* __restrict__ C, int M, int N, int K) {
  __shared__ __align__(16) char SM[65536];
  int l = threadIdx.x & 63;
  int lr = l & 15, lh = l >> 4;
  long m0 = (long)blockIdx.y * 128, n0 = (long)blockIdx.x * 128;
  f32x4 acc[4][4];
  int wm, wn;
  bool own = gemm_core(A, B, K, SM, m0, n0, wm, wn, acc);
  if (own) {
    #pragma unroll
    for (int mf = 0; mf < 4; mf++)
      #pragma unroll
      for (int nf = 0; nf < 4; nf++)
        #pragma unroll
        for (int i = 0; i < 4; i++)
          C[(m0 + wm * 64 + mf * 16 + lh * 4 + i) * N + n0 + wn * 64 + nf * 16 + lr] = acc[mf][nf][i];
  }
}

// QKV GEMM with fused RoPE + fp16 conversion + layout epilogue.
__global__ __launch_bounds__(512) void k_gemm_qkv(const unsigned short* __restrict__ A,
                                                  const unsigned short* __restrict__ B,
                                                  unsigned short* __restrict__ Qr,
                                                  unsigned short* __restrict__ Kr,
                                                  unsigned short* __restrict__ Vr,
                                                  const float* __restrict__ fc,
                                                  const float* __restrict__ fs, int K) {
  __shared__ __align__(16) char SM[65536];
  int l = threadIdx.x & 63;
  int lr = l & 15, lh = l >> 4;
  long m0 = (long)blockIdx.y * 128, n0 = (long)blockIdx.x * 128;
  f32x4 acc[4][4];
  int wm, wn;
  bool own = gemm_core(A, B, K, SM, m0, n0, wm, wn, acc);
  if (!own) return;

  const float SC = 0.125f * 1.44269504f;
  int n0i = (int)n0;
  if (n0i < 2560) {
    bool isQ = n0i < 2048;
    float scl = isQ ? SC : 1.0f;
    #pragma unroll
    for (int mf = 0; mf < 4; mf++)
      #pragma unroll
      for (int i = 0; i < 4; i++) {
        int row = (int)m0 + wm * 64 + mf * 16 + lh * 4 + i;
        const float* fcr = fc + row * 32;
        const float* fsr = fs + row * 32;
        #pragma unroll
        for (int nf = 0; nf < 4; nf++) {
          float v = acc[mf][nf][i];
          float pv = __shfl_xor(v, 1);
          int col = n0i + wn * 64 + nf * 16 + lr;
          int j = (col & 63) >> 1;
          float c_ = fcr[j] * scl, s_ = fsr[j] * scl;
          float o = (lr & 1) ? (pv * s_ + v * c_) : (v * c_ - pv * s_);
          if (isQ) Qr[(long)row * 2048 + col] = f2h(o);
          else {
            int cc = col - 2048;
            Kr[((long)(cc >> 6) * SEQ + row) * 64 + (cc & 63)] = f2h(o);
          }
        }
      }
  } else {
    #pragma unroll
    for (int mf = 0; mf < 4; mf++)
      #pragma unroll
      for (int i = 0; i < 4; i++) {
        int row = (int)m0 + wm * 64 + mf * 16 + lh * 4 + i;
        #pragma unroll
        for (int nf = 0; nf < 4; nf++) {
          int col = n0i + wn * 64 + nf * 16 + lr;
          Vr[(long)row * 512 + (col - 2560)] = f2h(acc[mf][nf][i]);
        }
      }
  }
}

// ---------------- attention sub-tile: swapped QK^T 32x32, no-max softmax, PV ----------------
// K LDS: [32 q-keys][8 chunks] XOR-swizzled (conflict-free). V LDS: chunk-major [4 c][64 d][8]
// (conflict-free by construction: lanes read consecutive d at 16B stride).
template <bool DG>
static __device__ __forceinline__ void attn_tile(const unsigned short* __restrict__ Ks,
                                                 const unsigned short* __restrict__ Vs,
                                                 int q, int hs, const half8 (&Qf)[4],
                                                 f32x16& O0, f32x16& O1, float& lsum) {
  half8 Kf[4], Vf[2][2];
  #pragma unroll
  for (int d = 0; d < 4; d++) {
    int e0 = d * 16 + 8 * hs;
    Kf[d] = *(const half8*)&Ks[q * 64 + (e0 ^ ((q & 7) << 3))];
  }
  #pragma unroll
  for (int ks = 0; ks < 2; ks++)
    #pragma unroll
    for (int nf = 0; nf < 2; nf++)
      Vf[ks][nf] = *(const half8*)&Vs[(2 * ks + hs) * 512 + (q + 32 * nf) * 8];

  f32x16 S;
  #pragma unroll
  for (int r = 0; r < 16; r++) S[r] = 0.f;
  #pragma unroll
  for (int d = 0; d < 4; d++)
    S = __builtin_amdgcn_mfma_f32_32x32x16_f16(Kf[d], Qf[d], S, 0, 0, 0);

  float p[16];
  #pragma unroll
  for (int r = 0; r < 16; r++) {
    float v = S[r];
    if (DG) {
      int key = (r & 3) + 8 * (r >> 2) + 4 * hs;
      if (key > q) v = -1e30f;
    }
    p[r] = __builtin_exp2f(v - 8.0f);
    lsum += p[r];
  }

  union { unsigned int u[4]; half8 hh; } f0, f1;
  #pragma unroll
  for (int c = 0; c < 4; c++) {
    f0.u[c] = pkh2(p[2 * c], p[2 * c + 1]);
    f1.u[c] = pkh2(p[8 + 2 * c], p[9 + 2 * c]);
  }

  O0 = __builtin_amdgcn_mfma_f32_32x32x16_f16(f0.hh, Vf[0][0], O0, 0, 0, 0);
  O0 = __builtin_amdgcn_mfma_f32_32x32x16_f16(f1.hh, Vf[1][0], O0, 0, 0, 0);
  O1 = __builtin_amdgcn_mfma_f32_32x32x16_f16(f0.hh, Vf[0][1], O1, 0, 0, 0);
  O1 = __builtin_amdgcn_mfma_f32_32x32x16_f16(f1.hh, Vf[1][1], O1, 0, 0, 0);
}

// ---------------- causal GQA flash attention: KVBLK=128 supers, dbuf LDS, branchless hot path ----------------
__global__ __launch_bounds__(256) void k_attn(const unsigned short* __restrict__ Qr,
                                              const unsigned short* __restrict__ Kr,
                                              const unsigned short* __restrict__ Vg,
                                              unsigned short* __restrict__ AO) {
  __shared__ unsigned short KT[2][8192];  // [4 subtiles][32 keys][8 chunks] swizzled
  __shared__ unsigned short VT[2][8192];  // [4 subtiles][4 chunks][64 d][8] chunk-major
  __shared__ float gbuf[4][32];

  int tt = threadIdx.x;
  int wid = tt >> 6, l = tt & 63;
  int q = l & 31, hs = l >> 5;
  int h = blockIdx.x, hkv = h >> 2;
  int by = (int)gridDim.y - 1 - blockIdx.y;  // longest blocks dispatch first
  int dt = 4 * by + wid;                     // this wave's diagonal kv-tile
  int q0 = by * 128 + wid * 32;

  const unsigned short* Kh = Kr + (long)hkv * SEQ * 64;
  const unsigned short* Vh = Vg + (long)hkv * 64 * SEQ;

  // staging sources: K pre-swizzled global (linear LDS dest); V chunk-major (c=tt>>6, d=tt&63)
  int skr = tt >> 3, skc = tt & 7;
  const unsigned short* Ksrc = Kh + (long)skr * 64 + ((skc * 8) ^ ((skr & 7) << 3));
  const unsigned short* Vsrc = Vh + (long)(tt & 63) * SEQ + ((tt >> 6) * 8);

#define ASTAGE(si) do { \
    int buf_ = (si) & 1; \
    _Pragma("unroll") for (int sub_ = 0; sub_ < 4; sub_++) { \
      int t0_ = ((si) * 4 + sub_) * 32; \
      gload16(Ksrc + (long)t0_ * 64, &KT[buf_][sub_ * 2048 + tt * 8]); \
      gload16(Vsrc + t0_, &VT[buf_][sub_ * 2048 + tt * 8]); \
    } \
  } while (0)

  half8 Qf[4];
  #pragma unroll
  for (int d = 0; d < 4; d++)
    Qf[d] = *(const half8*)&Qr[(long)(q0 + q) * 2048 + h * 64 + d * 16 + 8 * hs];

  f32x16 O0, O1;
  #pragma unroll
  for (int r = 0; r < 16; r++) { O0[r] = 0.f; O1[r] = 0.f; }
  float lsum = 0.f;

  ASTAGE(0);
  asm volatile("s_waitcnt vmcnt(0)" ::: "memory");
  __builtin_amdgcn_s_barrier();

  for (int si = 0; si <= by; si++) {
    if (si + 1 <= by) ASTAGE(si + 1);

    int buf = si & 1;
    const unsigned short* Kb = &KT[buf][0];
    const unsigned short* Vb = &VT[buf][0];
    int rem = dt - si * 4 + 1;  // subtiles this wave still owns in this super
    if (rem > 4) {              // hot path: 4 non-diag tiles, one straightline region
      attn_tile<false>(Kb, Vb, q, hs, Qf, O0, O1, lsum);
      attn_tile<false>(Kb + 2048, Vb + 2048, q, hs, Qf, O0, O1, lsum);
      attn_tile<false>(Kb + 4096, Vb + 4096, q, hs, Qf, O0, O1, lsum);
      attn_tile<false>(Kb + 6144, Vb + 6144, q, hs, Qf, O0, O1, lsum);
    } else if (rem > 0) {       // cold path: diagonal super
      for (int sub = 0; sub < rem - 1; sub++)
        attn_tile<false>(Kb + sub * 2048, Vb + sub * 2048, q, hs, Qf, O0, O1, lsum);
      attn_tile<true>(Kb + (rem - 1) * 2048, Vb + (rem - 1) * 2048, q, hs, Qf, O0, O1, lsum);
    }

    asm volatile("s_waitcnt vmcnt(0)" ::: "memory");  // next super's loads issued a full super ago
    __builtin_amdgcn_s_barrier();
  }
#undef ASTAGE

  // per-wave normalization (no cross-wave merge)
  lsum += __shfl_xor(lsum, 32);
  if (l < 32) gbuf[wid][l] = 1.f / lsum;
  asm volatile("" ::: "memory");
  #pragma unroll
  for (int r = 0; r < 16; r++) {
    int row = (r & 3) + 8 * (r >> 2) + 4 * hs;
    float ri = gbuf[wid][row];
    AO[(long)(q0 + row) * 2048 + h * 64 + q] = f2h(O0[r] * ri);
    AO[(long)(q0 + row) * 2048 + h * 64 + q + 32] = f2h(O1[r] * ri);
  }
}

extern "C" void kernel_launch(void* const* d_in, const int* in_sizes, int n_in,
                              void* d_out, int out_size, void* d_ws, size_t ws_size,
                              hipStream_t stream) {
  const float* x  = (const float*)d_in[0];
  const float* fc = (const float*)d_in[1];
  const float* fs = (const float*)d_in[2];
  const float* Wq = (const float*)d_in[4];
  const float* Wk = (const float*)d_in[5];
  const float* Wv = (const float*)d_in[6];
  const float* Wo = (const float*)d_in[7];
  float* out = (float*)d_out;

  char* ws = (char*)d_ws;
  unsigned short* xb  = (unsigned short*)(ws);                  // 8 MB (reused as AO later)
  unsigned short* WT  = (unsigned short*)(ws + (8l  << 20));    // 12 MB  [3072][2048] fp16
  unsigned short* WoT = (unsigned short*)(ws + (20l << 20));    // 8 MB   [2048][2048] fp16
  unsigned short* Qr  = (unsigned short*)(ws + (28l << 20));    // 8 MB   [S][2048] fp16
  unsigned short* Kr  = (unsigned short*)(ws + (36l << 20));    // 2 MB   [8][S][64] fp16
  unsigned short* Vr  = (unsigned short*)(ws + (38l << 20));    // 2 MB   [S][512] fp16
  unsigned short* Vt  = (unsigned short*)(ws + (40l << 20));    // 2 MB   [8][64][S] fp16 (key-permuted)
  unsigned short* AO  = xb;                                     // overlay: xb dead after QKV GEMM

  dim3 tb(32, 8);
  k_cvt<<<4096, 256, 0, stream>>>(x, xb, 2048 * 2048);
  k_tcvt<<<dim3(64, 64), tb, 0, stream>>>(Wq, WT, 2048, 2048, 2048);
  k_tcvt<<<dim3(16, 64), tb, 0, stream>>>(Wk, WT + 2048l * 2048, 2048, 512, 512);
  k_tcvt<<<dim3(16, 64), tb, 0, stream>>>(Wv, WT + 2560l * 2048, 2048, 512, 512);
  k_tcvt<<<dim3(64, 64), tb, 0, stream>>>(Wo, WoT, 2048, 2048, 2048);

  k_gemm_qkv<<<dim3(24, 16), 512, 0, stream>>>(xb, WT, Qr, Kr, Vr, fc, fs, 2048);

  k_tvp<<<dim3(16, 64), tb, 0, stream>>>(Vr, Vt);

  k_attn<<<dim3(32, 16), 256, 0, stream>>>(Qr, Kr, Vt, AO);

  k_gemm<<<dim3(16, 16), 512, 0, stream>>>(AO, WoT, out, 2048, 2048, 2048);
}

// Round 14
// 151.680 us; speedup vs baseline: 1.2777x; 1.0265x over previous
//
#include <hip/hip_runtime.h>

#define SEQ 2048
#define DMODEL 2048

typedef __attribute__((ext_vector_type(8))) _Float16 half8;
typedef __attribute__((ext_vector_type(4))) float f32x4;
typedef __attribute__((ext_vector_type(16))) float f32x16;

typedef const __attribute__((address_space(1))) void* gptr_t;
typedef __attribute__((address_space(3))) void* lptr_t;

static __device__ __forceinline__ void gload16(const void* g, void* l) {
  __builtin_amdgcn_global_load_lds((gptr_t)g, (lptr_t)l, 16, 0, 0);
}

static __device__ __forceinline__ unsigned short f2h(float f) {
  _Float16 h = (_Float16)f;
  union { _Float16 h; unsigned short u; } v; v.h = h;
  return v.u;
}

static __device__ __forceinline__ unsigned int pkh2(float a, float b) {
  union { __fp16 __attribute__((ext_vector_type(2))) h; unsigned int u; } v;
  v.h = __builtin_amdgcn_cvt_pkrtz(a, b);
  return v.u;
}

// ---------------- elementwise fp32 -> fp16 ----------------
__global__ void k_cvt(const float* __restrict__ in, unsigned short* __restrict__ out, int n) {
  int i = (blockIdx.x * 256 + threadIdx.x) * 4;
  if (i >= n) return;
  float4 v = *(const float4*)(in + i);
  ushort4 o;
  o.x = f2h(v.x); o.y = f2h(v.y); o.z = f2h(v.z); o.w = f2h(v.w);
  *(ushort4*)(out + i) = o;
}

// ---------------- tiled transpose + convert: in fp32 [K][N] -> out fp16 [N][K] ----------------
__global__ void k_tcvt(const float* __restrict__ in, unsigned short* __restrict__ out,
                       int K, int N, int ldin) {
  __shared__ float tile[32][33];
  int n0 = blockIdx.x * 32, k0 = blockIdx.y * 32;
  int tx = threadIdx.x, ty = threadIdx.y;  // 32 x 8
  #pragma unroll
  for (int j = ty; j < 32; j += 8)
    tile[j][tx] = in[(long)(k0 + j) * ldin + n0 + tx];
  __syncthreads();
  #pragma unroll
  for (int j = ty; j < 32; j += 8)
    out[(long)(n0 + j) * K + k0 + tx] = f2h(tile[tx][j]);
}

// ---------------- V transpose fp16 [S][512] -> Vt [8][64][S] with key permutation ----------------
__global__ void k_tvp(const unsigned short* __restrict__ in, unsigned short* __restrict__ out) {
  __shared__ unsigned short tile[32][33];
  int c0 = blockIdx.x * 32, s0 = blockIdx.y * 32;
  int tx = threadIdx.x, ty = threadIdx.y;  // 32 x 8
  #pragma unroll
  for (int j = ty; j < 32; j += 8)
    tile[j][tx] = in[(long)(s0 + j) * 512 + c0 + tx];
  __syncthreads();
  #pragma unroll
  for (int j = ty; j < 32; j += 8) {
    int c = c0 + j;
    int s = s0 + tx;
    int sp = (s & ~12) | ((s & 8) >> 1) | ((s & 4) << 1);
    out[((long)(c >> 6) * 64 + (c & 63)) * SEQ + sp] = tile[tx][j];
  }
}

// ---------------- GEMM core v2: 128x128 tile, BK=64, 8 waves = 2m x 2n x 2k-split ----------------
static __device__ __forceinline__ bool gemm_core(const unsigned short* __restrict__ A,
                                                 const unsigned short* __restrict__ B,
                                                 int K, char* SM, long m0, long n0,
                                                 int& wmO, int& wnO, f32x4 acc[4][4]) {
  int t = threadIdx.x;
  int l = t & 63, w = t >> 6;
  int ks = w & 1, wm = (w >> 2) & 1, wn = (w >> 1) & 1;
  int lr = l & 15, lh = l >> 4;
  wmO = wm; wnO = wn;
  unsigned short* As = (unsigned short*)SM;            // 2 x 8192 shorts
  unsigned short* Bs = (unsigned short*)(SM + 32768);  // 2 x 8192 shorts

  const unsigned short* Ag = A + (m0 + (t >> 3)) * K + (((t & 7) ^ ((t >> 3) & 7)) * 8);
  const unsigned short* Bg = B + (n0 + (t >> 3)) * K + (((t & 7) ^ ((t >> 3) & 7)) * 8);

  #pragma unroll
  for (int i = 0; i < 4; i++)
    #pragma unroll
    for (int j = 0; j < 4; j++)
      acc[i][j] = (f32x4){0.f, 0.f, 0.f, 0.f};

#define STG(buf, k0) do { \
    gload16(Ag + (k0), As + (buf) * 8192 + t * 8); \
    gload16(Ag + 64 * K + (k0), As + (buf) * 8192 + 4096 + t * 8); \
    gload16(Bg + (k0), Bs + (buf) * 8192 + t * 8); \
    gload16(Bg + 64 * K + (k0), Bs + (buf) * 8192 + 4096 + t * 8); \
  } while (0)

  int T = K >> 6;  // phases of BK=64
  STG(0, 0);
  asm volatile("s_waitcnt vmcnt(0)" ::: "memory");
  __builtin_amdgcn_s_barrier();

  for (int ph = 0; ph < T; ph++) {
    if (ph + 1 < T) STG((ph + 1) & 1, (ph + 1) * 64);
    const unsigned short* Ab = As + (ph & 1) * 8192;
    const unsigned short* Bb = Bs + (ph & 1) * 8192;
    half8 a[4], b[4];
    #pragma unroll
    for (int mf = 0; mf < 4; mf++) {
      int ra = wm * 64 + mf * 16 + lr;
      a[mf] = *(const half8*)&Ab[ra * 64 + (((ks * 4 + lh) ^ (ra & 7)) * 8)];
    }
    #pragma unroll
    for (int nf = 0; nf < 4; nf++) {
      int rb = wn * 64 + nf * 16 + lr;
      b[nf] = *(const half8*)&Bb[rb * 64 + (((ks * 4 + lh) ^ (rb & 7)) * 8)];
    }
    #pragma unroll
    for (int mf = 0; mf < 4; mf++)
      #pragma unroll
      for (int nf = 0; nf < 4; nf++)
        acc[mf][nf] = __builtin_amdgcn_mfma_f32_16x16x32_f16(a[mf], b[nf], acc[mf][nf], 0, 0, 0);
    asm volatile("s_waitcnt vmcnt(0)" ::: "memory");
    __builtin_amdgcn_s_barrier();
  }
#undef STG

  // ---- split-K reduction: ks=1 -> LDS -> ks=0 adds ----
  __syncthreads();
  float* red = (float*)SM;
  int p = wm * 2 + wn;
  if (ks == 1) {
    #pragma unroll
    for (int mf = 0; mf < 4; mf++)
      #pragma unroll
      for (int nf = 0; nf < 4; nf++)
        *(f32x4*)&red[p * 4096 + l * 64 + (((mf * 4 + nf) ^ (l & 15)) << 2)] = acc[mf][nf];
  }
  __syncthreads();
  if (ks == 0) {
    #pragma unroll
    for (int mf = 0; mf < 4; mf++)
      #pragma unroll
      for (int nf = 0; nf < 4; nf++)
        acc[mf][nf] += *(const f32x4*)&red[p * 4096 + l * 64 + (((mf * 4 + nf) ^ (l & 15)) << 2)];
  }
  return ks == 0;
}

// plain fp32-C GEMM (output projection)
__global__ __launch_bounds__(512) void k_gemm(const unsigned short* __restrict__ A,
                                              const unsigned short* __restrict__ B,
                                              float* __restrict__ C, int M, int N, int K) {
  __shared__ __align__(16) char SM[65536];
  int l = threadIdx.x & 63;
  int lr = l & 15, lh = l >> 4;
  long m0 = (long)blockIdx.y * 128, n0 = (long)blockIdx.x * 128;
  f32x4 acc[4][4];
  int wm, wn;
  bool own = gemm_core(A, B, K, SM, m0, n0, wm, wn, acc);
  if (own) {
    #pragma unroll
    for (int mf = 0; mf < 4; mf++)
      #pragma unroll
      for (int nf = 0; nf < 4; nf++)
        #pragma unroll
        for (int i = 0; i < 4; i++)
          C[(m0 + wm * 64 + mf * 16 + lh * 4 + i) * N + n0 + wn * 64 + nf * 16 + lr] = acc[mf][nf][i];
  }
}

// QKV GEMM with fused RoPE + fp16 conversion + layout epilogue.
__global__ __launch_bounds__(512) void k_gemm_qkv(const unsigned short* __restrict__ A,
                                                  const unsigned short* __restrict__ B,
                                                  unsigned short* __restrict__ Qr,
                                                  unsigned short* __restrict__ Kr,
                                                  unsigned short* __restrict__ Vr,
                                                  const float* __restrict__ fc,
                                                  const float* __restrict__ fs, int K) {
  __shared__ __align__(16) char SM[65536];
  int l = threadIdx.x & 63;
  int lr = l & 15, lh = l >> 4;
  long m0 = (long)blockIdx.y * 128, n0 = (long)blockIdx.x * 128;
  f32x4 acc[4][4];
  int wm, wn;
  bool own = gemm_core(A, B, K, SM, m0, n0, wm, wn, acc);
  if (!own) return;

  const float SC = 0.125f * 1.44269504f;
  int n0i = (int)n0;
  if (n0i < 2560) {
    bool isQ = n0i < 2048;
    float scl = isQ ? SC : 1.0f;
    #pragma unroll
    for (int mf = 0; mf < 4; mf++)
      #pragma unroll
      for (int i = 0; i < 4; i++) {
        int row = (int)m0 + wm * 64 + mf * 16 + lh * 4 + i;
        const float* fcr = fc + row * 32;
        const float* fsr = fs + row * 32;
        #pragma unroll
        for (int nf = 0; nf < 4; nf++) {
          float v = acc[mf][nf][i];
          float pv = __shfl_xor(v, 1);
          int col = n0i + wn * 64 + nf * 16 + lr;
          int j = (col & 63) >> 1;
          float c_ = fcr[j] * scl, s_ = fsr[j] * scl;
          float o = (lr & 1) ? (pv * s_ + v * c_) : (v * c_ - pv * s_);
          if (isQ) Qr[(long)row * 2048 + col] = f2h(o);
          else {
            int cc = col - 2048;
            Kr[((long)(cc >> 6) * SEQ + row) * 64 + (cc & 63)] = f2h(o);
          }
        }
      }
  } else {
    #pragma unroll
    for (int mf = 0; mf < 4; mf++)
      #pragma unroll
      for (int i = 0; i < 4; i++) {
        int row = (int)m0 + wm * 64 + mf * 16 + lh * 4 + i;
        #pragma unroll
        for (int nf = 0; nf < 4; nf++) {
          int col = n0i + wn * 64 + nf * 16 + lr;
          Vr[(long)row * 512 + (col - 2560)] = f2h(acc[mf][nf][i]);
        }
      }
  }
}

// ---------------- attention sub-tile: swapped QK^T 32x32, no-max softmax, PV ----------------
// lsum split into 4 accumulators to break the fp-add dependency chain (fp adds not reassociable).
template <bool DG>
static __device__ __forceinline__ void attn_tile(const unsigned short* __restrict__ Ks,
                                                 const unsigned short* __restrict__ Vs,
                                                 int q, int hs, const half8 (&Qf)[4],
                                                 f32x16& O0, f32x16& O1, f32x4& lsum4) {
  half8 Kf[4], Vf[2][2];
  #pragma unroll
  for (int d = 0; d < 4; d++) {
    int e0 = d * 16 + 8 * hs;
    Kf[d] = *(const half8*)&Ks[q * 64 + (e0 ^ ((q & 7) << 3))];
  }
  #pragma unroll
  for (int ks = 0; ks < 2; ks++)
    #pragma unroll
    for (int nf = 0; nf < 2; nf++)
      Vf[ks][nf] = *(const half8*)&Vs[(2 * ks + hs) * 512 + (q + 32 * nf) * 8];

  f32x16 S;
  #pragma unroll
  for (int r = 0; r < 16; r++) S[r] = 0.f;
  #pragma unroll
  for (int d = 0; d < 4; d++)
    S = __builtin_amdgcn_mfma_f32_32x32x16_f16(Kf[d], Qf[d], S, 0, 0, 0);

  float p[16];
  #pragma unroll
  for (int r = 0; r < 16; r++) {
    float v = S[r];
    if (DG) {
      int key = (r & 3) + 8 * (r >> 2) + 4 * hs;
      if (key > q) v = -1e30f;
    }
    p[r] = __builtin_exp2f(v - 8.0f);
    lsum4[r & 3] += p[r];
  }

  union { unsigned int u[4]; half8 hh; } f0, f1;
  #pragma unroll
  for (int c = 0; c < 4; c++) {
    f0.u[c] = pkh2(p[2 * c], p[2 * c + 1]);
    f1.u[c] = pkh2(p[8 + 2 * c], p[9 + 2 * c]);
  }

  O0 = __builtin_amdgcn_mfma_f32_32x32x16_f16(f0.hh, Vf[0][0], O0, 0, 0, 0);
  O0 = __builtin_amdgcn_mfma_f32_32x32x16_f16(f1.hh, Vf[1][0], O0, 0, 0, 0);
  O1 = __builtin_amdgcn_mfma_f32_32x32x16_f16(f0.hh, Vf[0][1], O1, 0, 0, 0);
  O1 = __builtin_amdgcn_mfma_f32_32x32x16_f16(f1.hh, Vf[1][1], O1, 0, 0, 0);
}

// ---------------- causal GQA flash attention: KV-split z=2, fp16 partials + f32 l-partials ----------------
// Grid (32 heads, 32): y -> by = 15-(y>>1) (longest first), z = y&1.
// Chunk z=0: supers [0, h8); z=1: [h8, by+1), h8 = ceil((by+1)/2). Longest chunk = 8 supers.
// No-max softmax => partials merge by plain addition in k_merge.
__global__ __launch_bounds__(256) void k_attn(const unsigned short* __restrict__ Qr,
                                              const unsigned short* __restrict__ Kr,
                                              const unsigned short* __restrict__ Vg,
                                              unsigned short* __restrict__ Op,
                                              float* __restrict__ Lp) {
  __shared__ unsigned short KT[2][8192];  // [4 subtiles][32 keys][8 chunks] swizzled
  __shared__ unsigned short VT[2][8192];  // [4 subtiles][4 chunks][64 d][8] chunk-major

  int tt = threadIdx.x;
  int wid = tt >> 6, l = tt & 63;
  int q = l & 31, hs = l >> 5;
  int h = blockIdx.x, hkv = h >> 2;
  int y = blockIdx.y;
  int by = 15 - (y >> 1), z = y & 1;
  int h8 = (by + 2) >> 1;
  int sb = z ? h8 : 0, se = z ? by + 1 : h8;  // super range [sb, se)
  int dt = 4 * by + wid;                      // this wave's diagonal kv-tile
  int q0 = by * 128 + wid * 32;

  const unsigned short* Kh = Kr + (long)hkv * SEQ * 64;
  const unsigned short* Vh = Vg + (long)hkv * 64 * SEQ;

  int skr = tt >> 3, skc = tt & 7;
  const unsigned short* Ksrc = Kh + (long)skr * 64 + ((skc * 8) ^ ((skr & 7) << 3));
  const unsigned short* Vsrc = Vh + (long)(tt & 63) * SEQ + ((tt >> 6) * 8);

#define ASTAGE(si) do { \
    int buf_ = (si) & 1; \
    _Pragma("unroll") for (int sub_ = 0; sub_ < 4; sub_++) { \
      int t0_ = ((si) * 4 + sub_) * 32; \
      gload16(Ksrc + (long)t0_ * 64, &KT[buf_][sub_ * 2048 + tt * 8]); \
      gload16(Vsrc + t0_, &VT[buf_][sub_ * 2048 + tt * 8]); \
    } \
  } while (0)

  half8 Qf[4];
  #pragma unroll
  for (int d = 0; d < 4; d++)
    Qf[d] = *(const half8*)&Qr[(long)(q0 + q) * 2048 + h * 64 + d * 16 + 8 * hs];

  f32x16 O0, O1;
  #pragma unroll
  for (int r = 0; r < 16; r++) { O0[r] = 0.f; O1[r] = 0.f; }
  f32x4 lsum4 = (f32x4){0.f, 0.f, 0.f, 0.f};

  if (sb < se) {
    ASTAGE(sb);
    asm volatile("s_waitcnt vmcnt(0)" ::: "memory");
    __builtin_amdgcn_s_barrier();

    for (int si = sb; si < se; si++) {
      if (si + 1 < se) ASTAGE(si + 1);

      int buf = si & 1;
      const unsigned short* Kb = &KT[buf][0];
      const unsigned short* Vb = &VT[buf][0];
      int rem = dt - si * 4 + 1;  // subtiles this wave still owns in this super
      if (rem > 4) {              // hot path: 4 non-diag tiles, one straightline region
        attn_tile<false>(Kb, Vb, q, hs, Qf, O0, O1, lsum4);
        attn_tile<false>(Kb + 2048, Vb + 2048, q, hs, Qf, O0, O1, lsum4);
        attn_tile<false>(Kb + 4096, Vb + 4096, q, hs, Qf, O0, O1, lsum4);
        attn_tile<false>(Kb + 6144, Vb + 6144, q, hs, Qf, O0, O1, lsum4);
      } else if (rem > 0) {       // cold path: diagonal super
        for (int sub = 0; sub < rem - 1; sub++)
          attn_tile<false>(Kb + sub * 2048, Vb + sub * 2048, q, hs, Qf, O0, O1, lsum4);
        attn_tile<true>(Kb + (rem - 1) * 2048, Vb + (rem - 1) * 2048, q, hs, Qf, O0, O1, lsum4);
      }

      asm volatile("s_waitcnt vmcnt(0)" ::: "memory");
      __builtin_amdgcn_s_barrier();
    }
  }
#undef ASTAGE

  // write raw partials (always, including empty chunks: buffers must be fully defined)
  float ls = lsum4[0] + lsum4[1] + lsum4[2] + lsum4[3];
  ls += __shfl_xor(ls, 32);
  if (l < 32) Lp[z * 65536 + h * 2048 + q0 + l] = ls;
  unsigned short* Oz = Op + (long)z * 2048 * 2048;
  #pragma unroll
  for (int r = 0; r < 16; r++) {
    int row = (r & 3) + 8 * (r >> 2) + 4 * hs;
    Oz[(long)(q0 + row) * 2048 + h * 64 + q] = f2h(O0[r]);
    Oz[(long)(q0 + row) * 2048 + h * 64 + q + 32] = f2h(O1[r]);
  }
}

// ---------------- merge: AO = (O0 + O1) / (l0 + l1) ----------------
__global__ void k_merge(const unsigned short* __restrict__ Op, const float* __restrict__ Lp,
                        unsigned short* __restrict__ AO) {
  int row = blockIdx.x, t = threadIdx.x;
  int col = t * 8, h = col >> 6;
  float li = 1.f / (Lp[h * 2048 + row] + Lp[65536 + h * 2048 + row]);
  half8 a = *(const half8*)&Op[(long)row * 2048 + col];
  half8 b = *(const half8*)&Op[4194304l + (long)row * 2048 + col];
  half8 o;
  #pragma unroll
  for (int j = 0; j < 8; j++)
    o[j] = (_Float16)(((float)a[j] + (float)b[j]) * li);
  *(half8*)&AO[(long)row * 2048 + col] = o;
}

extern "C" void kernel_launch(void* const* d_in, const int* in_sizes, int n_in,
                              void* d_out, int out_size, void* d_ws, size_t ws_size,
                              hipStream_t stream) {
  const float* x  = (const float*)d_in[0];
  const float* fc = (const float*)d_in[1];
  const float* fs = (const float*)d_in[2];
  const float* Wq = (const float*)d_in[4];
  const float* Wk = (const float*)d_in[5];
  const float* Wv = (const float*)d_in[6];
  const float* Wo = (const float*)d_in[7];
  float* out = (float*)d_out;

  char* ws = (char*)d_ws;
  unsigned short* xb  = (unsigned short*)(ws);                  // 8 MB (reused as AO later)
  unsigned short* WT  = (unsigned short*)(ws + (8l  << 20));    // 12 MB  [3072][2048] fp16
  unsigned short* WoT = (unsigned short*)(ws + (20l << 20));    // 8 MB   [2048][2048] fp16
  unsigned short* Qr  = (unsigned short*)(ws + (28l << 20));    // 8 MB   [S][2048] fp16
  unsigned short* Kr  = (unsigned short*)(ws + (36l << 20));    // 2 MB   [8][S][64] fp16
  unsigned short* Vr  = (unsigned short*)(ws + (38l << 20));    // 2 MB   [S][512] fp16
  unsigned short* Vt  = (unsigned short*)(ws + (40l << 20));    // 2 MB   [8][64][S] fp16 (key-permuted)
  unsigned short* Opp = (unsigned short*)(ws + (44l << 20));    // 16 MB  [2][S][2048] fp16 partials
  float*          Lp  = (float*)(ws + (60l << 20));             // 512 KB [2][32][S] f32 l-partials
  unsigned short* AO  = xb;                                     // overlay: xb dead after QKV GEMM

  dim3 tb(32, 8);
  k_cvt<<<4096, 256, 0, stream>>>(x, xb, 2048 * 2048);
  k_tcvt<<<dim3(64, 64), tb, 0, stream>>>(Wq, WT, 2048, 2048, 2048);
  k_tcvt<<<dim3(16, 64), tb, 0, stream>>>(Wk, WT + 2048l * 2048, 2048, 512, 512);
  k_tcvt<<<dim3(16, 64), tb, 0, stream>>>(Wv, WT + 2560l * 2048, 2048, 512, 512);
  k_tcvt<<<dim3(64, 64), tb, 0, stream>>>(Wo, WoT, 2048, 2048, 2048);

  k_gemm_qkv<<<dim3(24, 16), 512, 0, stream>>>(xb, WT, Qr, Kr, Vr, fc, fs, 2048);

  k_tvp<<<dim3(16, 64), tb, 0, stream>>>(Vr, Vt);

  k_attn<<<dim3(32, 32), 256, 0, stream>>>(Qr, Kr, Vt, Opp, Lp);
  k_merge<<<2048, 256, 0, stream>>>(Opp, Lp, AO);

  k_gemm<<<dim3(16, 16), 512, 0, stream>>>(AO, WoT, out, 2048, 2048, 2048);
}

// Round 15
// 149.077 us; speedup vs baseline: 1.3000x; 1.0175x over previous
//
#include <hip/hip_runtime.h>

#define SEQ 2048
#define DMODEL 2048

typedef __attribute__((ext_vector_type(8))) _Float16 half8;
typedef __attribute__((ext_vector_type(4))) float f32x4;
typedef __attribute__((ext_vector_type(16))) float f32x16;

typedef const __attribute__((address_space(1))) void* gptr_t;
typedef __attribute__((address_space(3))) void* lptr_t;

static __device__ __forceinline__ void gload16(const void* g, void* l) {
  __builtin_amdgcn_global_load_lds((gptr_t)g, (lptr_t)l, 16, 0, 0);
}

static __device__ __forceinline__ unsigned short f2h(float f) {
  _Float16 h = (_Float16)f;
  union { _Float16 h; unsigned short u; } v; v.h = h;
  return v.u;
}

static __device__ __forceinline__ unsigned int pkh2(float a, float b) {
  union { __fp16 __attribute__((ext_vector_type(2))) h; unsigned int u; } v;
  v.h = __builtin_amdgcn_cvt_pkrtz(a, b);
  return v.u;
}

// ---------------- elementwise fp32 -> fp16 ----------------
__global__ void k_cvt(const float* __restrict__ in, unsigned short* __restrict__ out, int n) {
  int i = (blockIdx.x * 256 + threadIdx.x) * 4;
  if (i >= n) return;
  float4 v = *(const float4*)(in + i);
  ushort4 o;
  o.x = f2h(v.x); o.y = f2h(v.y); o.z = f2h(v.z); o.w = f2h(v.w);
  *(ushort4*)(out + i) = o;
}

// ---------------- tiled transpose + convert: in fp32 [K][N] -> out fp16 [N][K] ----------------
__global__ void k_tcvt(const float* __restrict__ in, unsigned short* __restrict__ out,
                       int K, int N, int ldin) {
  __shared__ float tile[32][33];
  int n0 = blockIdx.x * 32, k0 = blockIdx.y * 32;
  int tx = threadIdx.x, ty = threadIdx.y;  // 32 x 8
  #pragma unroll
  for (int j = ty; j < 32; j += 8)
    tile[j][tx] = in[(long)(k0 + j) * ldin + n0 + tx];
  __syncthreads();
  #pragma unroll
  for (int j = ty; j < 32; j += 8)
    out[(long)(n0 + j) * K + k0 + tx] = f2h(tile[tx][j]);
}

// ---------------- V transpose fp16 [S][512] -> Vt [8][64][S] with key permutation ----------------
__global__ void k_tvp(const unsigned short* __restrict__ in, unsigned short* __restrict__ out) {
  __shared__ unsigned short tile[32][33];
  int c0 = blockIdx.x * 32, s0 = blockIdx.y * 32;
  int tx = threadIdx.x, ty = threadIdx.y;  // 32 x 8
  #pragma unroll
  for (int j = ty; j < 32; j += 8)
    tile[j][tx] = in[(long)(s0 + j) * 512 + c0 + tx];
  __syncthreads();
  #pragma unroll
  for (int j = ty; j < 32; j += 8) {
    int c = c0 + j;
    int s = s0 + tx;
    int sp = (s & ~12) | ((s & 8) >> 1) | ((s & 4) << 1);
    out[((long)(c >> 6) * 64 + (c & 63)) * SEQ + sp] = tile[tx][j];
  }
}

// ---------------- GEMM core v3: 128xBN tile (BN = NF*32), BK=64, 8 waves = 2m x 2n x 2k-split ----------------
// Each wave: 64 x (NF*16) output over its K-half. LDS: A 2x16KB + B 2x(BN*128B), SM fixed 64KB
// (reduction overlay needs it). XOR-swizzled chunks; linear LDS dest + pre-swizzled global source.
template <int NF>
static __device__ __forceinline__ bool gemm_core(const unsigned short* __restrict__ A,
                                                 const unsigned short* __restrict__ B,
                                                 int K, char* SM, long m0, long n0,
                                                 int& wmO, int& wnO, f32x4 acc[4][NF]) {
  constexpr int BN = NF * 32;
  int t = threadIdx.x;
  int l = t & 63, w = t >> 6;
  int ks = w & 1, wm = (w >> 2) & 1, wn = (w >> 1) & 1;
  int lr = l & 15, lh = l >> 4;
  wmO = wm; wnO = wn;
  unsigned short* As = (unsigned short*)SM;            // 2 x 8192 shorts
  unsigned short* Bs = (unsigned short*)(SM + 32768);  // 2 x BN*64 shorts

  const unsigned short* Ag = A + (m0 + (t >> 3)) * K + (((t & 7) ^ ((t >> 3) & 7)) * 8);
  const unsigned short* Bg = B + (n0 + (t >> 3)) * K + (((t & 7) ^ ((t >> 3) & 7)) * 8);

  #pragma unroll
  for (int i = 0; i < 4; i++)
    #pragma unroll
    for (int j = 0; j < NF; j++)
      acc[i][j] = (f32x4){0.f, 0.f, 0.f, 0.f};

#define STG(buf, k0) do { \
    gload16(Ag + (k0), As + (buf) * 8192 + t * 8); \
    gload16(Ag + 64 * K + (k0), As + (buf) * 8192 + 4096 + t * 8); \
    gload16(Bg + (k0), Bs + (buf) * (BN * 64) + t * 8); \
    if (t < (BN - 64) * 8) gload16(Bg + 64 * K + (k0), Bs + (buf) * (BN * 64) + 4096 + t * 8); \
  } while (0)

  int T = K >> 6;  // phases of BK=64
  STG(0, 0);
  asm volatile("s_waitcnt vmcnt(0)" ::: "memory");
  __builtin_amdgcn_s_barrier();

  for (int ph = 0; ph < T; ph++) {
    if (ph + 1 < T) STG((ph + 1) & 1, (ph + 1) * 64);
    const unsigned short* Ab = As + (ph & 1) * 8192;
    const unsigned short* Bb = Bs + (ph & 1) * (BN * 64);
    half8 a[4], b[NF];
    #pragma unroll
    for (int mf = 0; mf < 4; mf++) {
      int ra = wm * 64 + mf * 16 + lr;
      a[mf] = *(const half8*)&Ab[ra * 64 + (((ks * 4 + lh) ^ (ra & 7)) * 8)];
    }
    #pragma unroll
    for (int nf = 0; nf < NF; nf++) {
      int rb = wn * (NF * 16) + nf * 16 + lr;
      b[nf] = *(const half8*)&Bb[rb * 64 + (((ks * 4 + lh) ^ (rb & 7)) * 8)];
    }
    #pragma unroll
    for (int mf = 0; mf < 4; mf++)
      #pragma unroll
      for (int nf = 0; nf < NF; nf++)
        acc[mf][nf] = __builtin_amdgcn_mfma_f32_16x16x32_f16(a[mf], b[nf], acc[mf][nf], 0, 0, 0);
    asm volatile("s_waitcnt vmcnt(0)" ::: "memory");
    __builtin_amdgcn_s_barrier();
  }
#undef STG

  // ---- split-K reduction: ks=1 -> LDS -> ks=0 adds (16-slot sparse layout, XOR bijective) ----
  __syncthreads();
  float* red = (float*)SM;
  int p = wm * 2 + wn;
  if (ks == 1) {
    #pragma unroll
    for (int mf = 0; mf < 4; mf++)
      #pragma unroll
      for (int nf = 0; nf < NF; nf++)
        *(f32x4*)&red[p * 4096 + l * 64 + (((mf * 4 + nf) ^ (l & 15)) << 2)] = acc[mf][nf];
  }
  __syncthreads();
  if (ks == 0) {
    #pragma unroll
    for (int mf = 0; mf < 4; mf++)
      #pragma unroll
      for (int nf = 0; nf < NF; nf++)
        acc[mf][nf] += *(const f32x4*)&red[p * 4096 + l * 64 + (((mf * 4 + nf) ^ (l & 15)) << 2)];
  }
  return ks == 0;
}

// plain fp32-C GEMM (output projection), 128x128 tiles, grid 16x16, XCD chunked swizzle
__global__ __launch_bounds__(512) void k_gemm(const unsigned short* __restrict__ A,
                                              const unsigned short* __restrict__ B,
                                              float* __restrict__ C, int M, int N, int K) {
  __shared__ __align__(16) char SM[65536];
  int l = threadIdx.x & 63;
  int lr = l & 15, lh = l >> 4;
  int bid = blockIdx.y * 16 + blockIdx.x;
  int swz = (bid & 7) * 32 + (bid >> 3);  // nwg=256
  long m0 = (long)(swz >> 4) * 128, n0 = (long)(swz & 15) * 128;
  f32x4 acc[4][4];
  int wm, wn;
  bool own = gemm_core<4>(A, B, K, SM, m0, n0, wm, wn, acc);
  if (own) {
    #pragma unroll
    for (int mf = 0; mf < 4; mf++)
      #pragma unroll
      for (int nf = 0; nf < 4; nf++)
        #pragma unroll
        for (int i = 0; i < 4; i++)
          C[(m0 + wm * 64 + mf * 16 + lh * 4 + i) * N + n0 + wn * 64 + nf * 16 + lr] = acc[mf][nf][i];
  }
}

// QKV GEMM, 128x96 tiles (grid 32x16 = 512 blocks = 2/CU exact), XCD swizzle,
// fused RoPE + fp16 + layout epilogue with per-column-group Q/K/V routing.
__global__ __launch_bounds__(512) void k_gemm_qkv(const unsigned short* __restrict__ A,
                                                  const unsigned short* __restrict__ B,
                                                  unsigned short* __restrict__ Qr,
                                                  unsigned short* __restrict__ Kr,
                                                  unsigned short* __restrict__ Vr,
                                                  const float* __restrict__ fc,
                                                  const float* __restrict__ fs, int K) {
  __shared__ __align__(16) char SM[65536];
  int l = threadIdx.x & 63;
  int lr = l & 15, lh = l >> 4;
  int bid = blockIdx.y * 32 + blockIdx.x;
  int swz = (bid & 7) * 64 + (bid >> 3);  // nwg=512
  long m0 = (long)(swz >> 5) * 128, n0 = (long)(swz & 31) * 96;
  f32x4 acc[4][3];
  int wm, wn;
  bool own = gemm_core<3>(A, B, K, SM, m0, n0, wm, wn, acc);
  if (!own) return;

  const float SC = 0.125f * 1.44269504f;
  int n0i = (int)n0;
  #pragma unroll
  for (int mf = 0; mf < 4; mf++)
    #pragma unroll
    for (int i = 0; i < 4; i++) {
      int row = (int)m0 + wm * 64 + mf * 16 + lh * 4 + i;
      const float* fcr = fc + row * 32;
      const float* fsr = fs + row * 32;
      #pragma unroll
      for (int nf = 0; nf < 3; nf++) {
        float v = acc[mf][nf][i];
        int col = n0i + wn * 48 + nf * 16 + lr;
        if (col < 2560) {  // Q or K: rope (wave-uniform branch: boundaries are 16-multiples)
          float pv = __shfl_xor(v, 1);
          float scl = col < 2048 ? SC : 1.0f;
          int j = (col & 63) >> 1;
          float c_ = fcr[j] * scl, s_ = fsr[j] * scl;
          float o = (lr & 1) ? (pv * s_ + v * c_) : (v * c_ - pv * s_);
          if (col < 2048) {
            Qr[(long)row * 2048 + col] = f2h(o);
          } else {
            int cc = col - 2048;
            Kr[((long)(cc >> 6) * SEQ + row) * 64 + (cc & 63)] = f2h(o);
          }
        } else {  // V: plain fp16
          Vr[(long)row * 512 + (col - 2560)] = f2h(v);
        }
      }
    }
}

// ---------------- attention sub-tile: swapped QK^T 32x32, no-max softmax, PV ----------------
template <bool DG>
static __device__ __forceinline__ void attn_tile(const unsigned short* __restrict__ Ks,
                                                 const unsigned short* __restrict__ Vs,
                                                 int q, int hs, const half8 (&Qf)[4],
                                                 f32x16& O0, f32x16& O1, f32x4& lsum4) {
  half8 Kf[4], Vf[2][2];
  #pragma unroll
  for (int d = 0; d < 4; d++) {
    int e0 = d * 16 + 8 * hs;
    Kf[d] = *(const half8*)&Ks[q * 64 + (e0 ^ ((q & 7) << 3))];
  }
  #pragma unroll
  for (int ks = 0; ks < 2; ks++)
    #pragma unroll
    for (int nf = 0; nf < 2; nf++)
      Vf[ks][nf] = *(const half8*)&Vs[(2 * ks + hs) * 512 + (q + 32 * nf) * 8];

  f32x16 S;
  #pragma unroll
  for (int r = 0; r < 16; r++) S[r] = 0.f;
  #pragma unroll
  for (int d = 0; d < 4; d++)
    S = __builtin_amdgcn_mfma_f32_32x32x16_f16(Kf[d], Qf[d], S, 0, 0, 0);

  float p[16];
  #pragma unroll
  for (int r = 0; r < 16; r++) {
    float v = S[r];
    if (DG) {
      int key = (r & 3) + 8 * (r >> 2) + 4 * hs;
      if (key > q) v = -1e30f;
    }
    p[r] = __builtin_exp2f(v - 8.0f);
    lsum4[r & 3] += p[r];
  }

  union { unsigned int u[4]; half8 hh; } f0, f1;
  #pragma unroll
  for (int c = 0; c < 4; c++) {
    f0.u[c] = pkh2(p[2 * c], p[2 * c + 1]);
    f1.u[c] = pkh2(p[8 + 2 * c], p[9 + 2 * c]);
  }

  O0 = __builtin_amdgcn_mfma_f32_32x32x16_f16(f0.hh, Vf[0][0], O0, 0, 0, 0);
  O0 = __builtin_amdgcn_mfma_f32_32x32x16_f16(f1.hh, Vf[1][0], O0, 0, 0, 0);
  O1 = __builtin_amdgcn_mfma_f32_32x32x16_f16(f0.hh, Vf[0][1], O1, 0, 0, 0);
  O1 = __builtin_amdgcn_mfma_f32_32x32x16_f16(f1.hh, Vf[1][1], O1, 0, 0, 0);
}

// ---------------- causal GQA flash attention: KV-split z=2, fp16 partials + f32 l-partials ----------------
__global__ __launch_bounds__(256) void k_attn(const unsigned short* __restrict__ Qr,
                                              const unsigned short* __restrict__ Kr,
                                              const unsigned short* __restrict__ Vg,
                                              unsigned short* __restrict__ Op,
                                              float* __restrict__ Lp) {
  __shared__ unsigned short KT[2][8192];  // [4 subtiles][32 keys][8 chunks] swizzled
  __shared__ unsigned short VT[2][8192];  // [4 subtiles][4 chunks][64 d][8] chunk-major

  int tt = threadIdx.x;
  int wid = tt >> 6, l = tt & 63;
  int q = l & 31, hs = l >> 5;
  int h = blockIdx.x, hkv = h >> 2;
  int y = blockIdx.y;
  int by = 15 - (y >> 1), z = y & 1;
  int h8 = (by + 2) >> 1;
  int sb = z ? h8 : 0, se = z ? by + 1 : h8;  // super range [sb, se)
  int dt = 4 * by + wid;                      // this wave's diagonal kv-tile
  int q0 = by * 128 + wid * 32;

  const unsigned short* Kh = Kr + (long)hkv * SEQ * 64;
  const unsigned short* Vh = Vg + (long)hkv * 64 * SEQ;

  int skr = tt >> 3, skc = tt & 7;
  const unsigned short* Ksrc = Kh + (long)skr * 64 + ((skc * 8) ^ ((skr & 7) << 3));
  const unsigned short* Vsrc = Vh + (long)(tt & 63) * SEQ + ((tt >> 6) * 8);

#define ASTAGE(si) do { \
    int buf_ = (si) & 1; \
    _Pragma("unroll") for (int sub_ = 0; sub_ < 4; sub_++) { \
      int t0_ = ((si) * 4 + sub_) * 32; \
      gload16(Ksrc + (long)t0_ * 64, &KT[buf_][sub_ * 2048 + tt * 8]); \
      gload16(Vsrc + t0_, &VT[buf_][sub_ * 2048 + tt * 8]); \
    } \
  } while (0)

  half8 Qf[4];
  #pragma unroll
  for (int d = 0; d < 4; d++)
    Qf[d] = *(const half8*)&Qr[(long)(q0 + q) * 2048 + h * 64 + d * 16 + 8 * hs];

  f32x16 O0, O1;
  #pragma unroll
  for (int r = 0; r < 16; r++) { O0[r] = 0.f; O1[r] = 0.f; }
  f32x4 lsum4 = (f32x4){0.f, 0.f, 0.f, 0.f};

  if (sb < se) {
    ASTAGE(sb);
    asm volatile("s_waitcnt vmcnt(0)" ::: "memory");
    __builtin_amdgcn_s_barrier();

    for (int si = sb; si < se; si++) {
      if (si + 1 < se) ASTAGE(si + 1);

      int buf = si & 1;
      const unsigned short* Kb = &KT[buf][0];
      const unsigned short* Vb = &VT[buf][0];
      int rem = dt - si * 4 + 1;
      if (rem > 4) {
        attn_tile<false>(Kb, Vb, q, hs, Qf, O0, O1, lsum4);
        attn_tile<false>(Kb + 2048, Vb + 2048, q, hs, Qf, O0, O1, lsum4);
        attn_tile<false>(Kb + 4096, Vb + 4096, q, hs, Qf, O0, O1, lsum4);
        attn_tile<false>(Kb + 6144, Vb + 6144, q, hs, Qf, O0, O1, lsum4);
      } else if (rem > 0) {
        for (int sub = 0; sub < rem - 1; sub++)
          attn_tile<false>(Kb + sub * 2048, Vb + sub * 2048, q, hs, Qf, O0, O1, lsum4);
        attn_tile<true>(Kb + (rem - 1) * 2048, Vb + (rem - 1) * 2048, q, hs, Qf, O0, O1, lsum4);
      }

      asm volatile("s_waitcnt vmcnt(0)" ::: "memory");
      __builtin_amdgcn_s_barrier();
    }
  }
#undef ASTAGE

  float ls = lsum4[0] + lsum4[1] + lsum4[2] + lsum4[3];
  ls += __shfl_xor(ls, 32);
  if (l < 32) Lp[z * 65536 + h * 2048 + q0 + l] = ls;
  unsigned short* Oz = Op + (long)z * 2048 * 2048;
  #pragma unroll
  for (int r = 0; r < 16; r++) {
    int row = (r & 3) + 8 * (r >> 2) + 4 * hs;
    Oz[(long)(q0 + row) * 2048 + h * 64 + q] = f2h(O0[r]);
    Oz[(long)(q0 + row) * 2048 + h * 64 + q + 32] = f2h(O1[r]);
  }
}

// ---------------- merge: AO = (O0 + O1) / (l0 + l1) ----------------
__global__ void k_merge(const unsigned short* __restrict__ Op, const float* __restrict__ Lp,
                        unsigned short* __restrict__ AO) {
  int row = blockIdx.x, t = threadIdx.x;
  int col = t * 8, h = col >> 6;
  float li = 1.f / (Lp[h * 2048 + row] + Lp[65536 + h * 2048 + row]);
  half8 a = *(const half8*)&Op[(long)row * 2048 + col];
  half8 b = *(const half8*)&Op[4194304l + (long)row * 2048 + col];
  half8 o;
  #pragma unroll
  for (int j = 0; j < 8; j++)
    o[j] = (_Float16)(((float)a[j] + (float)b[j]) * li);
  *(half8*)&AO[(long)row * 2048 + col] = o;
}

extern "C" void kernel_launch(void* const* d_in, const int* in_sizes, int n_in,
                              void* d_out, int out_size, void* d_ws, size_t ws_size,
                              hipStream_t stream) {
  const float* x  = (const float*)d_in[0];
  const float* fc = (const float*)d_in[1];
  const float* fs = (const float*)d_in[2];
  const float* Wq = (const float*)d_in[4];
  const float* Wk = (const float*)d_in[5];
  const float* Wv = (const float*)d_in[6];
  const float* Wo = (const float*)d_in[7];
  float* out = (float*)d_out;

  char* ws = (char*)d_ws;
  unsigned short* xb  = (unsigned short*)(ws);                  // 8 MB (reused as AO later)
  unsigned short* WT  = (unsigned short*)(ws + (8l  << 20));    // 12 MB  [3072][2048] fp16
  unsigned short* WoT = (unsigned short*)(ws + (20l << 20));    // 8 MB   [2048][2048] fp16
  unsigned short* Qr  = (unsigned short*)(ws + (28l << 20));    // 8 MB   [S][2048] fp16
  unsigned short* Kr  = (unsigned short*)(ws + (36l << 20));    // 2 MB   [8][S][64] fp16
  unsigned short* Vr  = (unsigned short*)(ws + (38l << 20));    // 2 MB   [S][512] fp16
  unsigned short* Vt  = (unsigned short*)(ws + (40l << 20));    // 2 MB   [8][64][S] fp16 (key-permuted)
  unsigned short* Opp = (unsigned short*)(ws + (44l << 20));    // 16 MB  [2][S][2048] fp16 partials
  float*          Lp  = (float*)(ws + (60l << 20));             // 512 KB [2][32][S] f32 l-partials
  unsigned short* AO  = xb;                                     // overlay: xb dead after QKV GEMM

  dim3 tb(32, 8);
  k_cvt<<<4096, 256, 0, stream>>>(x, xb, 2048 * 2048);
  k_tcvt<<<dim3(64, 64), tb, 0, stream>>>(Wq, WT, 2048, 2048, 2048);
  k_tcvt<<<dim3(16, 64), tb, 0, stream>>>(Wk, WT + 2048l * 2048, 2048, 512, 512);
  k_tcvt<<<dim3(16, 64), tb, 0, stream>>>(Wv, WT + 2560l * 2048, 2048, 512, 512);
  k_tcvt<<<dim3(64, 64), tb, 0, stream>>>(Wo, WoT, 2048, 2048, 2048);

  k_gemm_qkv<<<dim3(32, 16), 512, 0, stream>>>(xb, WT, Qr, Kr, Vr, fc, fs, 2048);

  k_tvp<<<dim3(16, 64), tb, 0, stream>>>(Vr, Vt);

  k_attn<<<dim3(32, 32), 256, 0, stream>>>(Qr, Kr, Vt, Opp, Lp);
  k_merge<<<2048, 256, 0, stream>>>(Opp, Lp, AO);

  k_gemm<<<dim3(16, 16), 512, 0, stream>>>(AO, WoT, out, 2048, 2048, 2048);
}